// Round 11
// baseline (2213.686 us; speedup 1.0000x reference)
//
#include <hip/hip_runtime.h>
#include <math.h>

#define NNODES 50000
#define NEDGES 500000
#define DIM 128
#define NREL 51
#define NLAYERS 4
#define NTRIPLES (1024*32)
#define KDIM 1664     // 13*128
#define TILE_US 4096  // one B tile = 2 planes * 64 cols * 32 ushorts (swizzled 64B rows)
#define NBLK 196      // ceil(NNODES/256)

typedef float f2 __attribute__((ext_vector_type(2)));
typedef float f32x4 __attribute__((ext_vector_type(4)));
typedef short bf16x8 __attribute__((ext_vector_type(8)));

static __device__ __forceinline__ ushort bf16_rne(float v) {
  unsigned u = __float_as_uint(v);
  unsigned r = (u + 0x7fffu + ((u >> 16) & 1u)) >> 16;
  return (ushort)r;
}
static __device__ __forceinline__ float bf16_f(ushort h) {
  return __uint_as_float(((unsigned)h) << 16);
}
static __device__ __forceinline__ f2 fmax2(f2 a, f2 b) { f2 r; r.x = fmaxf(a.x,b.x); r.y = fmaxf(a.y,b.y); return r; }
static __device__ __forceinline__ f2 fmin2(f2 a, f2 b) { f2 r; r.x = fminf(a.x,b.x); r.y = fminf(a.y,b.y); return r; }

// async global->LDS, 16B per lane; LDS dest = wave-uniform base + lane*16 (linear layout only)
static __device__ __forceinline__ void gload_lds16(const void* g, void* l) {
  __builtin_amdgcn_global_load_lds(
      (const __attribute__((address_space(1))) unsigned int*)g,
      (__attribute__((address_space(3))) unsigned int*)l,
      16, 0, 0);
}

// ---------------- graph prep ----------------

__global__ void deg_hist_k(const int* __restrict__ ei, int* __restrict__ deg) {
  int e = blockIdx.x * blockDim.x + threadIdx.x;
  if (e < NEDGES) atomicAdd(&deg[ei[NEDGES + e]], 1);
}

__global__ void logsum_k(const int* __restrict__ deg, float* __restrict__ acc) {
  int i = blockIdx.x * blockDim.x + threadIdx.x;
  float v = (i < NNODES) ? logf((float)(deg[i] + 1)) : 0.0f;
  #pragma unroll
  for (int m = 32; m >= 1; m >>= 1) v += __shfl_xor(v, m, 64);
  __shared__ float ws[4];
  int lane = threadIdx.x & 63, w = threadIdx.x >> 6;
  if (lane == 0) ws[w] = v;
  __syncthreads();
  if (threadIdx.x == 0) atomicAdd(acc, ws[0] + ws[1] + ws[2] + ws[3]);
}

// ---- hierarchical scan: blocksum -> bscan -> csr_offsets ----

__global__ __launch_bounds__(256) void blocksum_k(const int* __restrict__ deg,
                                                  int* __restrict__ bsum) {
  int idx = blockIdx.x * 256 + threadIdx.x;
  int v = (idx < NNODES) ? deg[idx] : 0;
  #pragma unroll
  for (int m = 32; m >= 1; m >>= 1) v += __shfl_xor(v, m, 64);
  __shared__ int ws[4];
  int lane = threadIdx.x & 63, w = threadIdx.x >> 6;
  if (lane == 0) ws[w] = v;
  __syncthreads();
  if (threadIdx.x == 0) bsum[blockIdx.x] = ws[0] + ws[1] + ws[2] + ws[3];
}

__global__ __launch_bounds__(256) void bscan_k(const int* __restrict__ bsum,
                                               int* __restrict__ bofs) {
  int t = threadIdx.x;
  int v = (t < NBLK) ? bsum[t] : 0;
  int lane = t & 63, w = t >> 6;
  int sc = v;
  #pragma unroll
  for (int off = 1; off < 64; off <<= 1) {
    int u = __shfl_up(sc, off, 64);
    if (lane >= off) sc += u;
  }
  __shared__ int ws[4];
  if (lane == 63) ws[w] = sc;
  __syncthreads();
  int wo = 0;
  for (int i = 0; i < w; ++i) wo += ws[i];
  if (t < NBLK) bofs[t] = wo + sc - v;
}

__global__ __launch_bounds__(256) void csr_offsets_k(const int* __restrict__ deg,
                                                     const int* __restrict__ bofs,
                                                     int* __restrict__ row_start,
                                                     int* __restrict__ cursor) {
  int t = threadIdx.x;
  int idx = blockIdx.x * 256 + t;
  int v = (idx < NNODES) ? deg[idx] : 0;
  int lane = t & 63, w = t >> 6;
  int sc = v;
  #pragma unroll
  for (int off = 1; off < 64; off <<= 1) {
    int u = __shfl_up(sc, off, 64);
    if (lane >= off) sc += u;
  }
  __shared__ int ws[4];
  if (lane == 63) ws[w] = sc;
  __syncthreads();
  int wo = 0;
  for (int i = 0; i < w; ++i) wo += ws[i];
  int excl = bofs[blockIdx.x] + wo + sc - v;
  if (idx < NNODES) {
    row_start[idx] = excl;
    cursor[idx] = excl;
    if (idx == NNODES - 1) row_start[NNODES] = excl + v;
  }
}

__global__ void scales_k(const int* __restrict__ deg, const float* __restrict__ logsum,
                         float* __restrict__ scales) {
  int i = blockIdx.x * blockDim.x + threadIdx.x;
  if (i >= NNODES) return;
  float mean = *logsum / (float)NNODES;
  float sc = logf((float)(deg[i] + 1)) / mean;
  scales[i*3 + 0] = 1.0f;
  scales[i*3 + 1] = sc;
  scales[i*3 + 2] = 1.0f / fmaxf(sc, 0.01f);
}

__global__ void scatter_k(const int* __restrict__ ei, const int* __restrict__ etype,
                          const float* __restrict__ ew, int* __restrict__ cursor,
                          int* __restrict__ s_srt, int* __restrict__ t_srt,
                          float* __restrict__ w_srt) {
  int e = blockIdx.x * blockDim.x + threadIdx.x;
  if (e >= NEDGES) return;
  int d = ei[NEDGES + e];
  int pos = atomicAdd(&cursor[d], 1);
  s_srt[pos] = ei[e];
  t_srt[pos] = etype[e];
  w_srt[pos] = ew[e];
}

// ---------------- W pre-split into GEMM-ready swizzled tiles (R7 layout) ----------------

__global__ void wsplit_k(const float* __restrict__ W, ushort* __restrict__ wt) {
  int id = blockIdx.x * blockDim.x + threadIdx.x;
  if (id >= NLAYERS * KDIM * DIM) return;
  int col = id & 127;
  int k = (id >> 7) % KDIM;
  int l = id / (KDIM * DIM);
  float v = W[(size_t)l * KDIM * DIM + (size_t)k * DIM + col];
  ushort h = bf16_rne(v);
  ushort lo = bf16_rne(v - bf16_f(h));
  int c = k >> 5, kk = k & 31;
  int by = col >> 6, ch = col & 63;
  int tidx = (c < 48) ? ((c & 15) * 3 + (c >> 4)) : c;
  size_t base = (size_t)(((size_t)l * 2 + by) * 52 + tidx) * TILE_US;
  int slot = (kk >> 3) ^ ((ch >> 1) & 3);
  int off = ch * 32 + (slot << 3) + (kk & 7);
  wt[base + off] = h;
  wt[base + 2048 + off] = lo;
}

// ---------------- x -> bf16 hi/lo planes ----------------

__global__ void xsplit_k(const float* __restrict__ x, ushort* __restrict__ xh,
                         ushort* __restrict__ xl) {
  int id = blockIdx.x * blockDim.x + threadIdx.x;
  if (id >= NNODES * 64) return;
  f2 v = *(const f2*)(x + (size_t)id * 2);
  ushort h0 = bf16_rne(v.x), h1 = bf16_rne(v.y);
  ushort l0 = bf16_rne(v.x - bf16_f(h0)), l1 = bf16_rne(v.y - bf16_f(h1));
  ((uint*)xh)[id] = (uint)h0 | ((uint)h1 << 16);
  ((uint*)xl)[id] = (uint)l0 | ((uint)l1 << 16);
}

// ---------------- per-layer aggregation (one wave per destination node) ----------------

__global__ __launch_bounds__(256) void aggregate_k(
    const float* __restrict__ x, const float* __restrict__ x0,
    const float* __restrict__ relw, const int* __restrict__ row_start,
    const int* __restrict__ s_srt, const int* __restrict__ t_srt,
    const float* __restrict__ w_srt,
    ushort* __restrict__ sh, ushort* __restrict__ sl)
{
  int wid = blockIdx.x * 4 + (threadIdx.x >> 6);
  if (wid >= NNODES) return;
  int lane = threadIdx.x & 63;
  int j0 = lane * 2;
  int beg = row_start[wid], end = row_start[wid + 1];
  int deg = end - beg;
  f2 sum = {0.f, 0.f}, sq = {0.f, 0.f};
  f2 mx = {-INFINITY, -INFINITY}, mn = {INFINITY, INFINITY};

  // lane-parallel preload of up to 64 edge records
  int eidx = beg + lane;
  bool va = eidx < end;
  int   sv = va ? s_srt[eidx] : 0;
  int   tv = va ? t_srt[eidx] : 0;
  float wv = va ? w_srt[eidx] : 0.0f;

  int n = (deg < 64) ? deg : 64;
  int e = 0;
  for (; e + 4 <= n; e += 4) {
    int s0 = __shfl(sv, e, 64),     s1 = __shfl(sv, e + 1, 64);
    int s2 = __shfl(sv, e + 2, 64), s3 = __shfl(sv, e + 3, 64);
    int t0 = __shfl(tv, e, 64),     t1 = __shfl(tv, e + 1, 64);
    int t2 = __shfl(tv, e + 2, 64), t3 = __shfl(tv, e + 3, 64);
    float w0 = __shfl(wv, e, 64),     w1 = __shfl(wv, e + 1, 64);
    float w2 = __shfl(wv, e + 2, 64), w3 = __shfl(wv, e + 3, 64);
    f2 xa = *(const f2*)(x + (size_t)s0 * DIM + j0);
    f2 xb = *(const f2*)(x + (size_t)s1 * DIM + j0);
    f2 xc = *(const f2*)(x + (size_t)s2 * DIM + j0);
    f2 xd = *(const f2*)(x + (size_t)s3 * DIM + j0);
    f2 ra = *(const f2*)(relw + (size_t)t0 * DIM + j0);
    f2 rb = *(const f2*)(relw + (size_t)t1 * DIM + j0);
    f2 rc = *(const f2*)(relw + (size_t)t2 * DIM + j0);
    f2 rd = *(const f2*)(relw + (size_t)t3 * DIM + j0);
    f2 m0 = xa * ra * w0;
    f2 m1 = xb * rb * w1;
    f2 m2 = xc * rc * w2;
    f2 m3 = xd * rd * w3;
    sum += m0 + m1 + m2 + m3;
    sq += m0*m0 + m1*m1 + m2*m2 + m3*m3;
    mx = fmax2(fmax2(fmax2(mx, m0), fmax2(m1, m2)), m3);
    mn = fmin2(fmin2(fmin2(mn, m0), fmin2(m1, m2)), m3);
  }
  for (; e < n; ++e) {
    int s = __shfl(sv, e, 64);
    int ty = __shfl(tv, e, 64);
    float w = __shfl(wv, e, 64);
    f2 xs = *(const f2*)(x + (size_t)s * DIM + j0);
    f2 rv = *(const f2*)(relw + (size_t)ty * DIM + j0);
    f2 m = xs * rv * w;
    sum += m; sq += m * m;
    mx = fmax2(mx, m); mn = fmin2(mn, m);
  }
  // rare overflow path (deg > 64)
  for (int ee = beg + 64; ee < end; ++ee) {
    int s = s_srt[ee]; int ty = t_srt[ee]; float w = w_srt[ee];
    f2 xs = *(const f2*)(x + (size_t)s * DIM + j0);
    f2 rv = *(const f2*)(relw + (size_t)ty * DIM + j0);
    f2 m = xs * rv * w;
    sum += m; sq += m * m;
    mx = fmax2(mx, m); mn = fmin2(mn, m);
  }

  f2 x0v = *(const f2*)(x0 + (size_t)wid * DIM + j0);
  sum += x0v; sq += x0v * x0v;
  mx = fmax2(mx, x0v); mn = fmin2(mn, x0v);
  float dq = (float)(deg + 1);
  f2 mean = sum / dq;
  f2 sqm = sq / dq;
  f2 var = sqm - mean * mean;
  f2 sd; sd.x = sqrtf(fmaxf(var.x, 1e-6f)); sd.y = sqrtf(fmaxf(var.y, 1e-6f));
  f2 feats[4] = {mean, mx, mn, sd};
  size_t base = (size_t)wid * 512 + j0;
  #pragma unroll
  for (int f = 0; f < 4; ++f) {
    f2 v = feats[f];
    ushort h0 = bf16_rne(v.x), h1 = bf16_rne(v.y);
    ushort l0 = bf16_rne(v.x - bf16_f(h0)), l1 = bf16_rne(v.y - bf16_f(h1));
    *(uint*)(sh + base + f * 128) = (uint)h0 | ((uint)h1 << 16);
    *(uint*)(sl + base + f * 128) = (uint)l0 | ((uint)l1 << 16);
  }
}

// ---------------- scale-folded split-bf16 MFMA GEMM ----------------
// Block: 256 threads = 4 waves (2 row-groups x 2 col-groups), wave tile 64x32 (F_r=4).
// Block tile 128x64; LDS 40 KB (A 16 + B single-buf 24) -> 4 blocks/CU; the whole
// 782-block grid is co-resident (zero scheduling rounds); 4 independent blocks/CU
// hide each other's barrier drains (m97 regime). F_r=4 cuts total LDS reads 37%.
// Accumulators statically named (rule #20). Swizzle verified 0-conflict (R6).

__global__ __launch_bounds__(256, 4) void gemm_mfma_k(
    const ushort* __restrict__ sh, const ushort* __restrict__ sl,
    const ushort* __restrict__ xh, const ushort* __restrict__ xl,
    const float* __restrict__ scales, const ushort* __restrict__ wtl,
    float* __restrict__ Y)
{
  __shared__ ushort As[2 * 4096];      // hi [128][32], lo [128][32] (swizzled rows)
  __shared__ ushort Bs[3 * TILE_US];   // single-buffered, up to 3 s-tiles
  int t = threadIdx.x;
  int w = t >> 6, lane = t & 63;
  int lr = lane & 15, lk = lane >> 4;
  int rg = w >> 1, cg = w & 1;
  int row0 = blockIdx.x * 128;
  int by = blockIdx.y;

  // staging role: A row sr (0..127), slot pair sq2, sq2+1
  int sr = t >> 1, sq2 = (t & 1) * 2;
  int an = row0 + sr; if (an >= NNODES) an = NNODES - 1;
  int swzr = (sr >> 1) & 3;
  int aoff0 = sr * 32 + ((sq2 ^ swzr) << 3);
  int aoff1 = sr * 32 + (((sq2 + 1) ^ swzr) << 3);

  f32x4 a00,a01,a10,a11,a20,a21,a30,a31;   // s=0 partial: fr 0..3 x fc 0..1
  f32x4 b00,b01,b10,b11,b20,b21,b30,b31;   // s=1
  f32x4 c00,c01,c10,c11,c20,c21,c30,c31;   // s=2
  a00=a01=a10=a11=a20=a21=a30=a31=(f32x4){0.f,0.f,0.f,0.f};
  b00=b01=b10=b11=b20=b21=b30=b31=(f32x4){0.f,0.f,0.f,0.f};
  c00=c01=c10=c11=c20=c21=c30=c31=(f32x4){0.f,0.f,0.f,0.f};

  bf16x8 rh0, rh1, rl0, rl1;
  auto loadA = [&](int cp) {
    const ushort *ph, *pl;
    if (cp < 16) {
      size_t o = (size_t)an * 512 + cp * 32 + sq2 * 8;
      ph = sh + o;  pl = sl + o;
    } else {
      size_t o = (size_t)an * 128 + (cp - 16) * 32 + sq2 * 8;
      ph = xh + o;  pl = xl + o;
    }
    rh0 = *(const bf16x8*)ph;       rh1 = *(const bf16x8*)(ph + 8);
    rl0 = *(const bf16x8*)pl;       rl1 = *(const bf16x8*)(pl + 8);
  };
  auto writeA = [&]() {
    *(bf16x8*)(As + aoff0) = rh0;
    *(bf16x8*)(As + aoff1) = rh1;
    *(bf16x8*)(As + 4096 + aoff0) = rl0;
    *(bf16x8*)(As + 4096 + aoff1) = rl1;
  };
  auto issueB = [&](int cp) {
    int tile0 = (cp < 16) ? cp * 3 : cp + 32;
    const char* src = (const char*)(wtl + ((size_t)by * 52 + tile0) * TILE_US);
    char* d = (char*)Bs;
    gload_lds16(src + t * 16, d + t * 16);
    gload_lds16(src + (256 + t) * 16, d + (256 + t) * 16);
    if (cp < 16) {
      gload_lds16(src + (512 + t) * 16, d + (512 + t) * 16);
      gload_lds16(src + (768 + t) * 16, d + (768 + t) * 16);
      gload_lds16(src + (1024 + t) * 16, d + (1024 + t) * 16);
      gload_lds16(src + (1280 + t) * 16, d + (1280 + t) * 16);
    }
  };

  const int abase = (rg * 64 + lr) * 32 + ((lk ^ ((lr >> 1) & 3)) << 3);  // + fr*512
  const int bbase = (cg * 32 + lr) * 32 + ((lk ^ ((lr >> 1) & 3)) << 3);  // + fc*512

#define MFMA(d, va, vb) d = __builtin_amdgcn_mfma_f32_16x16x32_bf16(va, vb, d, 0,0,0)
#define DO_TILE(P00,P01,P10,P11,P20,P21,P30,P31, BT)                        \
  {                                                                          \
    const ushort* Bb = (BT) + bbase;                                         \
    bf16x8 bh0 = *(const bf16x8*)(Bb);                                       \
    bf16x8 bl0 = *(const bf16x8*)(Bb + 2048);                                \
    bf16x8 bh1 = *(const bf16x8*)(Bb + 512);                                 \
    bf16x8 bl1 = *(const bf16x8*)(Bb + 2048 + 512);                          \
    MFMA(P00, ah0, bh0); MFMA(P00, ah0, bl0); MFMA(P00, al0, bh0);           \
    MFMA(P01, ah0, bh1); MFMA(P01, ah0, bl1); MFMA(P01, al0, bh1);           \
    MFMA(P10, ah1, bh0); MFMA(P10, ah1, bl0); MFMA(P10, al1, bh0);           \
    MFMA(P11, ah1, bh1); MFMA(P11, ah1, bl1); MFMA(P11, al1, bh1);           \
    MFMA(P20, ah2, bh0); MFMA(P20, ah2, bl0); MFMA(P20, al2, bh0);           \
    MFMA(P21, ah2, bh1); MFMA(P21, ah2, bl1); MFMA(P21, al2, bh1);           \
    MFMA(P30, ah3, bh0); MFMA(P30, ah3, bl0); MFMA(P30, al3, bh0);           \
    MFMA(P31, ah3, bh1); MFMA(P31, ah3, bl1); MFMA(P31, al3, bh1);           \
  }

  loadA(0);
  for (int cp = 0; cp < 20; ++cp) {
    __syncthreads();   // all waves done reading As/Bs of previous chunk
    // ---- stage: A regs -> LDS; B via async global->LDS DMA ----
    writeA();
    issueB(cp);
    if (cp < 19) loadA(cp + 1);   // reg prefetch for next chunk (overlaps drain)
    __syncthreads();   // drains vmcnt (Bs ready) + lgkm (As written)
    // ---- compute ----
    const ushort* Ab = As + abase;
    bf16x8 ah0 = *(const bf16x8*)(Ab);
    bf16x8 ah1 = *(const bf16x8*)(Ab + 512);
    bf16x8 ah2 = *(const bf16x8*)(Ab + 1024);
    bf16x8 ah3 = *(const bf16x8*)(Ab + 1536);
    bf16x8 al0 = *(const bf16x8*)(Ab + 4096);
    bf16x8 al1 = *(const bf16x8*)(Ab + 4096 + 512);
    bf16x8 al2 = *(const bf16x8*)(Ab + 4096 + 1024);
    bf16x8 al3 = *(const bf16x8*)(Ab + 4096 + 1536);
    if (cp < 16) {
      DO_TILE(a00,a01,a10,a11,a20,a21,a30,a31, Bs);
      DO_TILE(b00,b01,b10,b11,b20,b21,b30,b31, Bs + TILE_US);
      DO_TILE(c00,c01,c10,c11,c20,c21,c30,c31, Bs + 2 * TILE_US);
    } else {
      DO_TILE(a00,a01,a10,a11,a20,a21,a30,a31, Bs);
    }
  }
#undef DO_TILE
#undef MFMA

  // ---- epilogue: fold scales, write Y ----
  int colg = by * 64 + cg * 32;
  f32x4 qa[4][2] = {{a00,a01},{a10,a11},{a20,a21},{a30,a31}};
  f32x4 qb[4][2] = {{b00,b01},{b10,b11},{b20,b21},{b30,b31}};
  f32x4 qc[4][2] = {{c00,c01},{c10,c11},{c20,c21},{c30,c31}};
  #pragma unroll
  for (int fr = 0; fr < 4; ++fr) {
    int rbase = row0 + rg * 64 + fr * 16 + lk * 4;
    #pragma unroll
    for (int q = 0; q < 4; ++q) {
      int r = rbase + q;
      int rc = (r < NNODES) ? r : (NNODES - 1);
      float s1 = scales[rc * 3 + 1];
      float s2 = scales[rc * 3 + 2];
      if (r < NNODES) {
        #pragma unroll
        for (int fc = 0; fc < 2; ++fc) {
          float o = qa[fr][fc][q] + s1 * qb[fr][fc][q] + s2 * qc[fr][fc][q];
          Y[(size_t)r * DIM + colg + fc * 16 + lr] = o;
        }
      }
    }
  }
}

// ---------------- bias + LN + relu + residual; also emit x hi/lo planes ----------------

__global__ __launch_bounds__(256) void ln_k(
    const float* __restrict__ Y, const float* __restrict__ bias,
    const float* __restrict__ gam, const float* __restrict__ bet,
    float* __restrict__ x, ushort* __restrict__ xh, ushort* __restrict__ xl)
{
  int wid = blockIdx.x * 4 + (threadIdx.x >> 6);
  if (wid >= NNODES) return;
  int lane = threadIdx.x & 63;
  int j0 = lane * 2;
  f2 v = *(const f2*)(Y + (size_t)wid * DIM + j0);
  f2 b = *(const f2*)(bias + j0);
  v += b;
  float s = v.x + v.y;
  float q = v.x * v.x + v.y * v.y;
  #pragma unroll
  for (int m = 1; m < 64; m <<= 1) { s += __shfl_xor(s, m, 64); q += __shfl_xor(q, m, 64); }
  float mu = s * (1.0f / 128.0f);
  float var = q * (1.0f / 128.0f) - mu * mu;
  float rstd = rsqrtf(var + 1e-5f);
  f2 g = *(const f2*)(gam + j0);
  f2 be = *(const f2*)(bet + j0);
  f2 o = (v - mu) * rstd * g + be;
  o.x = fmaxf(o.x, 0.f); o.y = fmaxf(o.y, 0.f);
  float* xp = x + (size_t)wid * DIM + j0;
  f2 xr = *(const f2*)xp;
  f2 res = o + xr;
  *(f2*)xp = res;
  ushort h0 = bf16_rne(res.x), h1 = bf16_rne(res.y);
  ushort l0 = bf16_rne(res.x - bf16_f(h0)), l1 = bf16_rne(res.y - bf16_f(h1));
  *(uint*)(xh + (size_t)wid * 128 + j0) = (uint)h0 | ((uint)h1 << 16);
  *(uint*)(xl + (size_t)wid * 128 + j0) = (uint)l0 | ((uint)l1 << 16);
}

// ---------------- distmult scoring ----------------

__global__ __launch_bounds__(256) void score_k(
    const float* __restrict__ x, const float* __restrict__ qw,
    const int* __restrict__ src, const int* __restrict__ rel,
    const int* __restrict__ dst, float* __restrict__ out)
{
  int wid = blockIdx.x * 4 + (threadIdx.x >> 6);
  if (wid >= NTRIPLES) return;
  int lane = threadIdx.x & 63;
  int j0 = lane * 2;
  int s = src[wid], r = rel[wid], d = dst[wid];
  f2 xs = *(const f2*)(x  + (size_t)s * DIM + j0);
  f2 q  = *(const f2*)(qw + (size_t)r * DIM + j0);
  f2 xd = *(const f2*)(x  + (size_t)d * DIM + j0);
  float p = xs.x*q.x*xd.x + xs.y*q.y*xd.y;
  #pragma unroll
  for (int m = 32; m >= 1; m >>= 1) p += __shfl_xor(p, m, 64);
  if (lane == 0) out[wid] = p;
}

// ---------------- launch ----------------

extern "C" void kernel_launch(void* const* d_in, const int* in_sizes, int n_in,
                              void* d_out, int out_size, void* d_ws, size_t ws_size,
                              hipStream_t stream) {
  const float* x0    = (const float*)d_in[0];
  const int*   ei    = (const int*)d_in[1];
  const int*   etyp  = (const int*)d_in[2];
  const float* ew    = (const float*)d_in[3];
  const float* rel_w = (const float*)d_in[4];
  const float* lin_w = (const float*)d_in[5];
  const float* lin_b = (const float*)d_in[6];
  const float* ln_g  = (const float*)d_in[7];
  const float* lnb   = (const float*)d_in[8];
  const float* qw    = (const float*)d_in[9];
  const int*   srcq  = (const int*)d_in[10];
  const int*   relq  = (const int*)d_in[11];
  const int*   dstq  = (const int*)d_in[12];
  float* out = (float*)d_out;

  char* ws = (char*)d_ws;
  size_t off = 0;
  auto alloc = [&](size_t bytes) -> void* {
    void* p = ws + off; off = (off + bytes + 255) & ~(size_t)255; return p;
  };
  int*    deg       = (int*)alloc((size_t)NNODES * 4);
  int*    row_start = (int*)alloc((size_t)(NNODES + 1) * 4);
  int*    cursor    = (int*)alloc((size_t)NNODES * 4);
  int*    bsum      = (int*)alloc((size_t)(NBLK + 1) * 4);
  int*    bofs      = (int*)alloc((size_t)(NBLK + 1) * 4);
  int*    s_srt     = (int*)alloc((size_t)NEDGES * 4);
  int*    t_srt     = (int*)alloc((size_t)NEDGES * 4);
  float*  w_srt     = (float*)alloc((size_t)NEDGES * 4);
  float*  scales    = (float*)alloc((size_t)NNODES * 3 * 4);
  float*  logsum    = (float*)alloc(256);
  ushort* stats_hi  = (ushort*)alloc((size_t)NNODES * 512 * 2);
  ushort* stats_lo  = (ushort*)alloc((size_t)NNODES * 512 * 2);
  float*  xbuf      = (float*)alloc((size_t)NNODES * DIM * 4);
  ushort* xhi       = (ushort*)alloc((size_t)NNODES * DIM * 2);
  ushort* xlo       = (ushort*)alloc((size_t)NNODES * DIM * 2);
  float*  Ybuf      = (float*)alloc((size_t)NNODES * DIM * 4);
  ushort* wtbuf     = (ushort*)alloc((size_t)NLAYERS * 2 * 52 * TILE_US * 2);

  hipMemsetAsync(deg, 0, (size_t)NNODES * 4, stream);
  hipMemsetAsync(logsum, 0, 4, stream);
  deg_hist_k<<<(NEDGES + 255) / 256, 256, 0, stream>>>(ei, deg);
  logsum_k<<<(NNODES + 255) / 256, 256, 0, stream>>>(deg, logsum);
  blocksum_k<<<NBLK, 256, 0, stream>>>(deg, bsum);
  bscan_k<<<1, 256, 0, stream>>>(bsum, bofs);
  csr_offsets_k<<<NBLK, 256, 0, stream>>>(deg, bofs, row_start, cursor);
  scales_k<<<(NNODES + 255) / 256, 256, 0, stream>>>(deg, logsum, scales);
  scatter_k<<<(NEDGES + 255) / 256, 256, 0, stream>>>(ei, etyp, ew, cursor, s_srt, t_srt, w_srt);
  wsplit_k<<<(NLAYERS * KDIM * DIM + 255) / 256, 256, 0, stream>>>(lin_w, wtbuf);
  hipMemcpyAsync(xbuf, x0, (size_t)NNODES * DIM * 4, hipMemcpyDeviceToDevice, stream);
  xsplit_k<<<(NNODES * 64 + 255) / 256, 256, 0, stream>>>(x0, xhi, xlo);

  for (int l = 0; l < NLAYERS; ++l) {
    aggregate_k<<<(NNODES + 3) / 4, 256, 0, stream>>>(
        xbuf, x0, rel_w + (size_t)l * NREL * DIM, row_start, s_srt, t_srt, w_srt,
        stats_hi, stats_lo);
    dim3 gg((NNODES + 127) / 128, 2);
    gemm_mfma_k<<<gg, 256, 0, stream>>>(
        stats_hi, stats_lo, xhi, xlo, scales,
        wtbuf + (size_t)l * 2 * 52 * TILE_US, Ybuf);
    ln_k<<<(NNODES + 3) / 4, 256, 0, stream>>>(
        Ybuf, lin_b + (size_t)l * DIM, ln_g + (size_t)l * DIM, lnb + (size_t)l * DIM,
        xbuf, xhi, xlo);
  }
  score_k<<<(NTRIPLES + 3) / 4, 256, 0, stream>>>(xbuf, qw, srcq, relq, dstq, out);
}

// Round 12
// 1483.939 us; speedup vs baseline: 1.4918x; 1.4918x over previous
//
#include <hip/hip_runtime.h>
#include <math.h>

#define NNODES 50000
#define NEDGES 500000
#define DIM 128
#define NREL 51
#define NLAYERS 4
#define NTRIPLES (1024*32)
#define KDIM 1664     // 13*128
#define TILE_US 4096  // one B tile = 2 planes * 64 cols * 32 ushorts (swizzled 64B rows)
#define NBLK 196      // ceil(NNODES/256)

typedef float f2 __attribute__((ext_vector_type(2)));
typedef float f32x4 __attribute__((ext_vector_type(4)));
typedef short bf16x8 __attribute__((ext_vector_type(8)));

static __device__ __forceinline__ ushort bf16_rne(float v) {
  unsigned u = __float_as_uint(v);
  unsigned r = (u + 0x7fffu + ((u >> 16) & 1u)) >> 16;
  return (ushort)r;
}
static __device__ __forceinline__ float bf16_f(ushort h) {
  return __uint_as_float(((unsigned)h) << 16);
}
static __device__ __forceinline__ f2 fmax2(f2 a, f2 b) { f2 r; r.x = fmaxf(a.x,b.x); r.y = fmaxf(a.y,b.y); return r; }
static __device__ __forceinline__ f2 fmin2(f2 a, f2 b) { f2 r; r.x = fminf(a.x,b.x); r.y = fminf(a.y,b.y); return r; }

// async global->LDS, 16B per lane; LDS dest = wave-uniform base + lane*16 (linear layout only)
static __device__ __forceinline__ void gload_lds16(const void* g, void* l) {
  __builtin_amdgcn_global_load_lds(
      (const __attribute__((address_space(1))) unsigned int*)g,
      (__attribute__((address_space(3))) unsigned int*)l,
      16, 0, 0);
}

// ---------------- graph prep ----------------

__global__ void deg_hist_k(const int* __restrict__ ei, int* __restrict__ deg) {
  int e = blockIdx.x * blockDim.x + threadIdx.x;
  if (e < NEDGES) atomicAdd(&deg[ei[NEDGES + e]], 1);
}

__global__ void logsum_k(const int* __restrict__ deg, float* __restrict__ acc) {
  int i = blockIdx.x * blockDim.x + threadIdx.x;
  float v = (i < NNODES) ? logf((float)(deg[i] + 1)) : 0.0f;
  #pragma unroll
  for (int m = 32; m >= 1; m >>= 1) v += __shfl_xor(v, m, 64);
  __shared__ float ws[4];
  int lane = threadIdx.x & 63, w = threadIdx.x >> 6;
  if (lane == 0) ws[w] = v;
  __syncthreads();
  if (threadIdx.x == 0) atomicAdd(acc, ws[0] + ws[1] + ws[2] + ws[3]);
}

// ---- hierarchical scan: blocksum -> bscan -> csr_offsets ----

__global__ __launch_bounds__(256) void blocksum_k(const int* __restrict__ deg,
                                                  int* __restrict__ bsum) {
  int idx = blockIdx.x * 256 + threadIdx.x;
  int v = (idx < NNODES) ? deg[idx] : 0;
  #pragma unroll
  for (int m = 32; m >= 1; m >>= 1) v += __shfl_xor(v, m, 64);
  __shared__ int ws[4];
  int lane = threadIdx.x & 63, w = threadIdx.x >> 6;
  if (lane == 0) ws[w] = v;
  __syncthreads();
  if (threadIdx.x == 0) bsum[blockIdx.x] = ws[0] + ws[1] + ws[2] + ws[3];
}

__global__ __launch_bounds__(256) void bscan_k(const int* __restrict__ bsum,
                                               int* __restrict__ bofs) {
  int t = threadIdx.x;
  int v = (t < NBLK) ? bsum[t] : 0;
  int lane = t & 63, w = t >> 6;
  int sc = v;
  #pragma unroll
  for (int off = 1; off < 64; off <<= 1) {
    int u = __shfl_up(sc, off, 64);
    if (lane >= off) sc += u;
  }
  __shared__ int ws[4];
  if (lane == 63) ws[w] = sc;
  __syncthreads();
  int wo = 0;
  for (int i = 0; i < w; ++i) wo += ws[i];
  if (t < NBLK) bofs[t] = wo + sc - v;
}

__global__ __launch_bounds__(256) void csr_offsets_k(const int* __restrict__ deg,
                                                     const int* __restrict__ bofs,
                                                     int* __restrict__ row_start,
                                                     int* __restrict__ cursor) {
  int t = threadIdx.x;
  int idx = blockIdx.x * 256 + t;
  int v = (idx < NNODES) ? deg[idx] : 0;
  int lane = t & 63, w = t >> 6;
  int sc = v;
  #pragma unroll
  for (int off = 1; off < 64; off <<= 1) {
    int u = __shfl_up(sc, off, 64);
    if (lane >= off) sc += u;
  }
  __shared__ int ws[4];
  if (lane == 63) ws[w] = sc;
  __syncthreads();
  int wo = 0;
  for (int i = 0; i < w; ++i) wo += ws[i];
  int excl = bofs[blockIdx.x] + wo + sc - v;
  if (idx < NNODES) {
    row_start[idx] = excl;
    cursor[idx] = excl;
    if (idx == NNODES - 1) row_start[NNODES] = excl + v;
  }
}

__global__ void scales_k(const int* __restrict__ deg, const float* __restrict__ logsum,
                         float* __restrict__ scales) {
  int i = blockIdx.x * blockDim.x + threadIdx.x;
  if (i >= NNODES) return;
  float mean = *logsum / (float)NNODES;
  float sc = logf((float)(deg[i] + 1)) / mean;
  scales[i*3 + 0] = 1.0f;
  scales[i*3 + 1] = sc;
  scales[i*3 + 2] = 1.0f / fmaxf(sc, 0.01f);
}

__global__ void scatter_k(const int* __restrict__ ei, const int* __restrict__ etype,
                          const float* __restrict__ ew, int* __restrict__ cursor,
                          int* __restrict__ s_srt, int* __restrict__ t_srt,
                          float* __restrict__ w_srt) {
  int e = blockIdx.x * blockDim.x + threadIdx.x;
  if (e >= NEDGES) return;
  int d = ei[NEDGES + e];
  int pos = atomicAdd(&cursor[d], 1);
  s_srt[pos] = ei[e];
  t_srt[pos] = etype[e];
  w_srt[pos] = ew[e];
}

// ---------------- W pre-split into GEMM-ready swizzled tiles (R7 layout) ----------------

__global__ void wsplit_k(const float* __restrict__ W, ushort* __restrict__ wt) {
  int id = blockIdx.x * blockDim.x + threadIdx.x;
  if (id >= NLAYERS * KDIM * DIM) return;
  int col = id & 127;
  int k = (id >> 7) % KDIM;
  int l = id / (KDIM * DIM);
  float v = W[(size_t)l * KDIM * DIM + (size_t)k * DIM + col];
  ushort h = bf16_rne(v);
  ushort lo = bf16_rne(v - bf16_f(h));
  int c = k >> 5, kk = k & 31;
  int by = col >> 6, ch = col & 63;
  int tidx = (c < 48) ? ((c & 15) * 3 + (c >> 4)) : c;
  size_t base = (size_t)(((size_t)l * 2 + by) * 52 + tidx) * TILE_US;
  int slot = (kk >> 3) ^ ((ch >> 1) & 3);
  int off = ch * 32 + (slot << 3) + (kk & 7);
  wt[base + off] = h;
  wt[base + 2048 + off] = lo;
}

// ---------------- x -> bf16 hi/lo planes ----------------

__global__ void xsplit_k(const float* __restrict__ x, ushort* __restrict__ xh,
                         ushort* __restrict__ xl) {
  int id = blockIdx.x * blockDim.x + threadIdx.x;
  if (id >= NNODES * 64) return;
  f2 v = *(const f2*)(x + (size_t)id * 2);
  ushort h0 = bf16_rne(v.x), h1 = bf16_rne(v.y);
  ushort l0 = bf16_rne(v.x - bf16_f(h0)), l1 = bf16_rne(v.y - bf16_f(h1));
  ((uint*)xh)[id] = (uint)h0 | ((uint)h1 << 16);
  ((uint*)xl)[id] = (uint)l0 | ((uint)l1 << 16);
}

// ---------------- per-layer aggregation (one wave per destination node) ----------------

__global__ __launch_bounds__(256) void aggregate_k(
    const float* __restrict__ x, const float* __restrict__ x0,
    const float* __restrict__ relw, const int* __restrict__ row_start,
    const int* __restrict__ s_srt, const int* __restrict__ t_srt,
    const float* __restrict__ w_srt,
    ushort* __restrict__ sh, ushort* __restrict__ sl)
{
  int wid = blockIdx.x * 4 + (threadIdx.x >> 6);
  if (wid >= NNODES) return;
  int lane = threadIdx.x & 63;
  int j0 = lane * 2;
  int beg = row_start[wid], end = row_start[wid + 1];
  int deg = end - beg;
  f2 sum = {0.f, 0.f}, sq = {0.f, 0.f};
  f2 mx = {-INFINITY, -INFINITY}, mn = {INFINITY, INFINITY};

  // lane-parallel preload of up to 64 edge records
  int eidx = beg + lane;
  bool va = eidx < end;
  int   sv = va ? s_srt[eidx] : 0;
  int   tv = va ? t_srt[eidx] : 0;
  float wv = va ? w_srt[eidx] : 0.0f;

  int n = (deg < 64) ? deg : 64;
  int e = 0;
  for (; e + 4 <= n; e += 4) {
    int s0 = __shfl(sv, e, 64),     s1 = __shfl(sv, e + 1, 64);
    int s2 = __shfl(sv, e + 2, 64), s3 = __shfl(sv, e + 3, 64);
    int t0 = __shfl(tv, e, 64),     t1 = __shfl(tv, e + 1, 64);
    int t2 = __shfl(tv, e + 2, 64), t3 = __shfl(tv, e + 3, 64);
    float w0 = __shfl(wv, e, 64),     w1 = __shfl(wv, e + 1, 64);
    float w2 = __shfl(wv, e + 2, 64), w3 = __shfl(wv, e + 3, 64);
    f2 xa = *(const f2*)(x + (size_t)s0 * DIM + j0);
    f2 xb = *(const f2*)(x + (size_t)s1 * DIM + j0);
    f2 xc = *(const f2*)(x + (size_t)s2 * DIM + j0);
    f2 xd = *(const f2*)(x + (size_t)s3 * DIM + j0);
    f2 ra = *(const f2*)(relw + (size_t)t0 * DIM + j0);
    f2 rb = *(const f2*)(relw + (size_t)t1 * DIM + j0);
    f2 rc = *(const f2*)(relw + (size_t)t2 * DIM + j0);
    f2 rd = *(const f2*)(relw + (size_t)t3 * DIM + j0);
    f2 m0 = xa * ra * w0;
    f2 m1 = xb * rb * w1;
    f2 m2 = xc * rc * w2;
    f2 m3 = xd * rd * w3;
    sum += m0 + m1 + m2 + m3;
    sq += m0*m0 + m1*m1 + m2*m2 + m3*m3;
    mx = fmax2(fmax2(fmax2(mx, m0), fmax2(m1, m2)), m3);
    mn = fmin2(fmin2(fmin2(mn, m0), fmin2(m1, m2)), m3);
  }
  for (; e < n; ++e) {
    int s = __shfl(sv, e, 64);
    int ty = __shfl(tv, e, 64);
    float w = __shfl(wv, e, 64);
    f2 xs = *(const f2*)(x + (size_t)s * DIM + j0);
    f2 rv = *(const f2*)(relw + (size_t)ty * DIM + j0);
    f2 m = xs * rv * w;
    sum += m; sq += m * m;
    mx = fmax2(mx, m); mn = fmin2(mn, m);
  }
  // rare overflow path (deg > 64)
  for (int ee = beg + 64; ee < end; ++ee) {
    int s = s_srt[ee]; int ty = t_srt[ee]; float w = w_srt[ee];
    f2 xs = *(const f2*)(x + (size_t)s * DIM + j0);
    f2 rv = *(const f2*)(relw + (size_t)ty * DIM + j0);
    f2 m = xs * rv * w;
    sum += m; sq += m * m;
    mx = fmax2(mx, m); mn = fmin2(mn, m);
  }

  f2 x0v = *(const f2*)(x0 + (size_t)wid * DIM + j0);
  sum += x0v; sq += x0v * x0v;
  mx = fmax2(mx, x0v); mn = fmin2(mn, x0v);
  float dq = (float)(deg + 1);
  f2 mean = sum / dq;
  f2 sqm = sq / dq;
  f2 var = sqm - mean * mean;
  f2 sd; sd.x = sqrtf(fmaxf(var.x, 1e-6f)); sd.y = sqrtf(fmaxf(var.y, 1e-6f));
  f2 feats[4] = {mean, mx, mn, sd};
  size_t base = (size_t)wid * 512 + j0;
  #pragma unroll
  for (int f = 0; f < 4; ++f) {
    f2 v = feats[f];
    ushort h0 = bf16_rne(v.x), h1 = bf16_rne(v.y);
    ushort l0 = bf16_rne(v.x - bf16_f(h0)), l1 = bf16_rne(v.y - bf16_f(h1));
    *(uint*)(sh + base + f * 128) = (uint)h0 | ((uint)h1 << 16);
    *(uint*)(sl + base + f * 128) = (uint)l0 | ((uint)l1 << 16);
  }
}

// ---------------- scale-folded split-bf16 MFMA GEMM ----------------
// Block: 256 threads = 4 waves (2 row-groups x 2 col-groups), wave tile 64x32 (F_r=4).
// Block tile 128x64; LDS 40 KB (A 16 + B single-buf 24).
// __launch_bounds__(256, 3): VGPR cap 170 (need ~110-140; (256,4)'s 128 cap spilled
// in R11 -> 1 GB scratch). 3 blocks/CU -> 782 blocks / 768 slots = 1.02 rounds;
// F_r=4 cuts total LDS reads 37%. Static acc names (rule #20). Swizzle 0-conflict.

__global__ __launch_bounds__(256, 3) void gemm_mfma_k(
    const ushort* __restrict__ sh, const ushort* __restrict__ sl,
    const ushort* __restrict__ xh, const ushort* __restrict__ xl,
    const float* __restrict__ scales, const ushort* __restrict__ wtl,
    float* __restrict__ Y)
{
  __shared__ ushort As[2 * 4096];      // hi [128][32], lo [128][32] (swizzled rows)
  __shared__ ushort Bs[3 * TILE_US];   // single-buffered, up to 3 s-tiles
  int t = threadIdx.x;
  int w = t >> 6, lane = t & 63;
  int lr = lane & 15, lk = lane >> 4;
  int rg = w >> 1, cg = w & 1;
  int row0 = blockIdx.x * 128;
  int by = blockIdx.y;

  // staging role: A row sr (0..127), slot pair sq2, sq2+1
  int sr = t >> 1, sq2 = (t & 1) * 2;
  int an = row0 + sr; if (an >= NNODES) an = NNODES - 1;
  int swzr = (sr >> 1) & 3;
  int aoff0 = sr * 32 + ((sq2 ^ swzr) << 3);
  int aoff1 = sr * 32 + (((sq2 + 1) ^ swzr) << 3);

  f32x4 a00,a01,a10,a11,a20,a21,a30,a31;   // s=0 partial: fr 0..3 x fc 0..1
  f32x4 b00,b01,b10,b11,b20,b21,b30,b31;   // s=1
  f32x4 c00,c01,c10,c11,c20,c21,c30,c31;   // s=2
  a00=a01=a10=a11=a20=a21=a30=a31=(f32x4){0.f,0.f,0.f,0.f};
  b00=b01=b10=b11=b20=b21=b30=b31=(f32x4){0.f,0.f,0.f,0.f};
  c00=c01=c10=c11=c20=c21=c30=c31=(f32x4){0.f,0.f,0.f,0.f};

  bf16x8 rh0, rh1, rl0, rl1;
  auto loadA = [&](int cp) {
    const ushort *ph, *pl;
    if (cp < 16) {
      size_t o = (size_t)an * 512 + cp * 32 + sq2 * 8;
      ph = sh + o;  pl = sl + o;
    } else {
      size_t o = (size_t)an * 128 + (cp - 16) * 32 + sq2 * 8;
      ph = xh + o;  pl = xl + o;
    }
    rh0 = *(const bf16x8*)ph;       rh1 = *(const bf16x8*)(ph + 8);
    rl0 = *(const bf16x8*)pl;       rl1 = *(const bf16x8*)(pl + 8);
  };
  auto writeA = [&]() {
    *(bf16x8*)(As + aoff0) = rh0;
    *(bf16x8*)(As + aoff1) = rh1;
    *(bf16x8*)(As + 4096 + aoff0) = rl0;
    *(bf16x8*)(As + 4096 + aoff1) = rl1;
  };
  auto issueB = [&](int cp) {
    int tile0 = (cp < 16) ? cp * 3 : cp + 32;
    const char* src = (const char*)(wtl + ((size_t)by * 52 + tile0) * TILE_US);
    char* d = (char*)Bs;
    gload_lds16(src + t * 16, d + t * 16);
    gload_lds16(src + (256 + t) * 16, d + (256 + t) * 16);
    if (cp < 16) {
      gload_lds16(src + (512 + t) * 16, d + (512 + t) * 16);
      gload_lds16(src + (768 + t) * 16, d + (768 + t) * 16);
      gload_lds16(src + (1024 + t) * 16, d + (1024 + t) * 16);
      gload_lds16(src + (1280 + t) * 16, d + (1280 + t) * 16);
    }
  };

  const int abase = (rg * 64 + lr) * 32 + ((lk ^ ((lr >> 1) & 3)) << 3);  // + fr*512
  const int bbase = (cg * 32 + lr) * 32 + ((lk ^ ((lr >> 1) & 3)) << 3);  // + fc*512

#define MFMA(d, va, vb) d = __builtin_amdgcn_mfma_f32_16x16x32_bf16(va, vb, d, 0,0,0)
#define DO_TILE(P00,P01,P10,P11,P20,P21,P30,P31, BT)                        \
  {                                                                          \
    const ushort* Bb = (BT) + bbase;                                         \
    bf16x8 bh0 = *(const bf16x8*)(Bb);                                       \
    bf16x8 bl0 = *(const bf16x8*)(Bb + 2048);                                \
    bf16x8 bh1 = *(const bf16x8*)(Bb + 512);                                 \
    bf16x8 bl1 = *(const bf16x8*)(Bb + 2048 + 512);                          \
    MFMA(P00, ah0, bh0); MFMA(P00, ah0, bl0); MFMA(P00, al0, bh0);           \
    MFMA(P01, ah0, bh1); MFMA(P01, ah0, bl1); MFMA(P01, al0, bh1);           \
    MFMA(P10, ah1, bh0); MFMA(P10, ah1, bl0); MFMA(P10, al1, bh0);           \
    MFMA(P11, ah1, bh1); MFMA(P11, ah1, bl1); MFMA(P11, al1, bh1);           \
    MFMA(P20, ah2, bh0); MFMA(P20, ah2, bl0); MFMA(P20, al2, bh0);           \
    MFMA(P21, ah2, bh1); MFMA(P21, ah2, bl1); MFMA(P21, al2, bh1);           \
    MFMA(P30, ah3, bh0); MFMA(P30, ah3, bl0); MFMA(P30, al3, bh0);           \
    MFMA(P31, ah3, bh1); MFMA(P31, ah3, bl1); MFMA(P31, al3, bh1);           \
  }

  loadA(0);
  for (int cp = 0; cp < 20; ++cp) {
    __syncthreads();   // all waves done reading As/Bs of previous chunk
    // ---- stage: A regs -> LDS; B via async global->LDS DMA ----
    writeA();
    issueB(cp);
    if (cp < 19) loadA(cp + 1);   // reg prefetch for next chunk (overlaps drain)
    __syncthreads();   // drains vmcnt (Bs ready) + lgkm (As written)
    // ---- compute ----
    const ushort* Ab = As + abase;
    bf16x8 ah0 = *(const bf16x8*)(Ab);
    bf16x8 ah1 = *(const bf16x8*)(Ab + 512);
    bf16x8 ah2 = *(const bf16x8*)(Ab + 1024);
    bf16x8 ah3 = *(const bf16x8*)(Ab + 1536);
    bf16x8 al0 = *(const bf16x8*)(Ab + 4096);
    bf16x8 al1 = *(const bf16x8*)(Ab + 4096 + 512);
    bf16x8 al2 = *(const bf16x8*)(Ab + 4096 + 1024);
    bf16x8 al3 = *(const bf16x8*)(Ab + 4096 + 1536);
    if (cp < 16) {
      DO_TILE(a00,a01,a10,a11,a20,a21,a30,a31, Bs);
      DO_TILE(b00,b01,b10,b11,b20,b21,b30,b31, Bs + TILE_US);
      DO_TILE(c00,c01,c10,c11,c20,c21,c30,c31, Bs + 2 * TILE_US);
    } else {
      DO_TILE(a00,a01,a10,a11,a20,a21,a30,a31, Bs);
    }
  }
#undef DO_TILE
#undef MFMA

  // ---- epilogue: fold scales, write Y ----
  int colg = by * 64 + cg * 32;
  f32x4 qa[4][2] = {{a00,a01},{a10,a11},{a20,a21},{a30,a31}};
  f32x4 qb[4][2] = {{b00,b01},{b10,b11},{b20,b21},{b30,b31}};
  f32x4 qc[4][2] = {{c00,c01},{c10,c11},{c20,c21},{c30,c31}};
  #pragma unroll
  for (int fr = 0; fr < 4; ++fr) {
    int rbase = row0 + rg * 64 + fr * 16 + lk * 4;
    #pragma unroll
    for (int q = 0; q < 4; ++q) {
      int r = rbase + q;
      int rc = (r < NNODES) ? r : (NNODES - 1);
      float s1 = scales[rc * 3 + 1];
      float s2 = scales[rc * 3 + 2];
      if (r < NNODES) {
        #pragma unroll
        for (int fc = 0; fc < 2; ++fc) {
          float o = qa[fr][fc][q] + s1 * qb[fr][fc][q] + s2 * qc[fr][fc][q];
          Y[(size_t)r * DIM + colg + fc * 16 + lr] = o;
        }
      }
    }
  }
}

// ---------------- bias + LN + relu + residual; also emit x hi/lo planes ----------------

__global__ __launch_bounds__(256) void ln_k(
    const float* __restrict__ Y, const float* __restrict__ bias,
    const float* __restrict__ gam, const float* __restrict__ bet,
    float* __restrict__ x, ushort* __restrict__ xh, ushort* __restrict__ xl)
{
  int wid = blockIdx.x * 4 + (threadIdx.x >> 6);
  if (wid >= NNODES) return;
  int lane = threadIdx.x & 63;
  int j0 = lane * 2;
  f2 v = *(const f2*)(Y + (size_t)wid * DIM + j0);
  f2 b = *(const f2*)(bias + j0);
  v += b;
  float s = v.x + v.y;
  float q = v.x * v.x + v.y * v.y;
  #pragma unroll
  for (int m = 1; m < 64; m <<= 1) { s += __shfl_xor(s, m, 64); q += __shfl_xor(q, m, 64); }
  float mu = s * (1.0f / 128.0f);
  float var = q * (1.0f / 128.0f) - mu * mu;
  float rstd = rsqrtf(var + 1e-5f);
  f2 g = *(const f2*)(gam + j0);
  f2 be = *(const f2*)(bet + j0);
  f2 o = (v - mu) * rstd * g + be;
  o.x = fmaxf(o.x, 0.f); o.y = fmaxf(o.y, 0.f);
  float* xp = x + (size_t)wid * DIM + j0;
  f2 xr = *(const f2*)xp;
  f2 res = o + xr;
  *(f2*)xp = res;
  ushort h0 = bf16_rne(res.x), h1 = bf16_rne(res.y);
  ushort l0 = bf16_rne(res.x - bf16_f(h0)), l1 = bf16_rne(res.y - bf16_f(h1));
  *(uint*)(xh + (size_t)wid * 128 + j0) = (uint)h0 | ((uint)h1 << 16);
  *(uint*)(xl + (size_t)wid * 128 + j0) = (uint)l0 | ((uint)l1 << 16);
}

// ---------------- distmult scoring ----------------

__global__ __launch_bounds__(256) void score_k(
    const float* __restrict__ x, const float* __restrict__ qw,
    const int* __restrict__ src, const int* __restrict__ rel,
    const int* __restrict__ dst, float* __restrict__ out)
{
  int wid = blockIdx.x * 4 + (threadIdx.x >> 6);
  if (wid >= NTRIPLES) return;
  int lane = threadIdx.x & 63;
  int j0 = lane * 2;
  int s = src[wid], r = rel[wid], d = dst[wid];
  f2 xs = *(const f2*)(x  + (size_t)s * DIM + j0);
  f2 q  = *(const f2*)(qw + (size_t)r * DIM + j0);
  f2 xd = *(const f2*)(x  + (size_t)d * DIM + j0);
  float p = xs.x*q.x*xd.x + xs.y*q.y*xd.y;
  #pragma unroll
  for (int m = 32; m >= 1; m >>= 1) p += __shfl_xor(p, m, 64);
  if (lane == 0) out[wid] = p;
}

// ---------------- launch ----------------

extern "C" void kernel_launch(void* const* d_in, const int* in_sizes, int n_in,
                              void* d_out, int out_size, void* d_ws, size_t ws_size,
                              hipStream_t stream) {
  const float* x0    = (const float*)d_in[0];
  const int*   ei    = (const int*)d_in[1];
  const int*   etyp  = (const int*)d_in[2];
  const float* ew    = (const float*)d_in[3];
  const float* rel_w = (const float*)d_in[4];
  const float* lin_w = (const float*)d_in[5];
  const float* lin_b = (const float*)d_in[6];
  const float* ln_g  = (const float*)d_in[7];
  const float* lnb   = (const float*)d_in[8];
  const float* qw    = (const float*)d_in[9];
  const int*   srcq  = (const int*)d_in[10];
  const int*   relq  = (const int*)d_in[11];
  const int*   dstq  = (const int*)d_in[12];
  float* out = (float*)d_out;

  char* ws = (char*)d_ws;
  size_t off = 0;
  auto alloc = [&](size_t bytes) -> void* {
    void* p = ws + off; off = (off + bytes + 255) & ~(size_t)255; return p;
  };
  int*    deg       = (int*)alloc((size_t)NNODES * 4);
  int*    row_start = (int*)alloc((size_t)(NNODES + 1) * 4);
  int*    cursor    = (int*)alloc((size_t)NNODES * 4);
  int*    bsum      = (int*)alloc((size_t)(NBLK + 1) * 4);
  int*    bofs      = (int*)alloc((size_t)(NBLK + 1) * 4);
  int*    s_srt     = (int*)alloc((size_t)NEDGES * 4);
  int*    t_srt     = (int*)alloc((size_t)NEDGES * 4);
  float*  w_srt     = (float*)alloc((size_t)NEDGES * 4);
  float*  scales    = (float*)alloc((size_t)NNODES * 3 * 4);
  float*  logsum    = (float*)alloc(256);
  ushort* stats_hi  = (ushort*)alloc((size_t)NNODES * 512 * 2);
  ushort* stats_lo  = (ushort*)alloc((size_t)NNODES * 512 * 2);
  float*  xbuf      = (float*)alloc((size_t)NNODES * DIM * 4);
  ushort* xhi       = (ushort*)alloc((size_t)NNODES * DIM * 2);
  ushort* xlo       = (ushort*)alloc((size_t)NNODES * DIM * 2);
  float*  Ybuf      = (float*)alloc((size_t)NNODES * DIM * 4);
  ushort* wtbuf     = (ushort*)alloc((size_t)NLAYERS * 2 * 52 * TILE_US * 2);

  hipMemsetAsync(deg, 0, (size_t)NNODES * 4, stream);
  hipMemsetAsync(logsum, 0, 4, stream);
  deg_hist_k<<<(NEDGES + 255) / 256, 256, 0, stream>>>(ei, deg);
  logsum_k<<<(NNODES + 255) / 256, 256, 0, stream>>>(deg, logsum);
  blocksum_k<<<NBLK, 256, 0, stream>>>(deg, bsum);
  bscan_k<<<1, 256, 0, stream>>>(bsum, bofs);
  csr_offsets_k<<<NBLK, 256, 0, stream>>>(deg, bofs, row_start, cursor);
  scales_k<<<(NNODES + 255) / 256, 256, 0, stream>>>(deg, logsum, scales);
  scatter_k<<<(NEDGES + 255) / 256, 256, 0, stream>>>(ei, etyp, ew, cursor, s_srt, t_srt, w_srt);
  wsplit_k<<<(NLAYERS * KDIM * DIM + 255) / 256, 256, 0, stream>>>(lin_w, wtbuf);
  hipMemcpyAsync(xbuf, x0, (size_t)NNODES * DIM * 4, hipMemcpyDeviceToDevice, stream);
  xsplit_k<<<(NNODES * 64 + 255) / 256, 256, 0, stream>>>(x0, xhi, xlo);

  for (int l = 0; l < NLAYERS; ++l) {
    aggregate_k<<<(NNODES + 3) / 4, 256, 0, stream>>>(
        xbuf, x0, rel_w + (size_t)l * NREL * DIM, row_start, s_srt, t_srt, w_srt,
        stats_hi, stats_lo);
    dim3 gg((NNODES + 127) / 128, 2);
    gemm_mfma_k<<<gg, 256, 0, stream>>>(
        stats_hi, stats_lo, xhi, xlo, scales,
        wtbuf + (size_t)l * 2 * 52 * TILE_US, Ybuf);
    ln_k<<<(NNODES + 3) / 4, 256, 0, stream>>>(
        Ybuf, lin_b + (size_t)l * DIM, ln_g + (size_t)l * DIM, lnb + (size_t)l * DIM,
        xbuf, xhi, xlo);
  }
  score_k<<<(NTRIPLES + 3) / 4, 256, 0, stream>>>(xbuf, qw, srcq, relq, dstq, out);
}

// Round 13
// 890.126 us; speedup vs baseline: 2.4869x; 1.6671x over previous
//
#include <hip/hip_runtime.h>
#include <math.h>

#define NNODES 50000
#define NEDGES 500000
#define DIM 128
#define NREL 51
#define NLAYERS 4
#define NTRIPLES (1024*32)
#define KDIM 1664     // 13*128
#define TILE_US 4096  // one B tile = 2 planes * 64 rows * 32 ushorts (swizzled 64B rows)
#define NBLK 196      // ceil(NNODES/256)
#define SLICE_N 6250  // nodes per L2 slice (3.2 MB < 4 MB per-XCD L2)

typedef float f2 __attribute__((ext_vector_type(2)));
typedef float f32x4 __attribute__((ext_vector_type(4)));
typedef short bf16x8 __attribute__((ext_vector_type(8)));

static __device__ __forceinline__ ushort bf16_rne(float v) {
  unsigned u = __float_as_uint(v);
  unsigned r = (u + 0x7fffu + ((u >> 16) & 1u)) >> 16;
  return (ushort)r;
}
static __device__ __forceinline__ float bf16_f(ushort h) {
  return __uint_as_float(((unsigned)h) << 16);
}
static __device__ __forceinline__ f2 fmax2(f2 a, f2 b) { f2 r; r.x = fmaxf(a.x,b.x); r.y = fmaxf(a.y,b.y); return r; }
static __device__ __forceinline__ f2 fmin2(f2 a, f2 b) { f2 r; r.x = fminf(a.x,b.x); r.y = fminf(a.y,b.y); return r; }

// async global->LDS, 16B per lane; LDS dest = wave-uniform base + lane*16 (linear layout only)
static __device__ __forceinline__ void gload_lds16(const void* g, void* l) {
  __builtin_amdgcn_global_load_lds(
      (const __attribute__((address_space(1))) unsigned int*)g,
      (__attribute__((address_space(3))) unsigned int*)l,
      16, 0, 0);
}

// ---------------- graph prep ----------------

__global__ void deg_hist_k(const int* __restrict__ ei, int* __restrict__ deg) {
  int e = blockIdx.x * blockDim.x + threadIdx.x;
  if (e < NEDGES) atomicAdd(&deg[ei[NEDGES + e]], 1);
}

__global__ void logsum_k(const int* __restrict__ deg, float* __restrict__ acc) {
  int i = blockIdx.x * blockDim.x + threadIdx.x;
  float v = (i < NNODES) ? logf((float)(deg[i] + 1)) : 0.0f;
  #pragma unroll
  for (int m = 32; m >= 1; m >>= 1) v += __shfl_xor(v, m, 64);
  __shared__ float ws[4];
  int lane = threadIdx.x & 63, w = threadIdx.x >> 6;
  if (lane == 0) ws[w] = v;
  __syncthreads();
  if (threadIdx.x == 0) atomicAdd(acc, ws[0] + ws[1] + ws[2] + ws[3]);
}

// ---- hierarchical scan: blocksum -> bscan -> csr_offsets ----

__global__ __launch_bounds__(256) void blocksum_k(const int* __restrict__ deg,
                                                  int* __restrict__ bsum) {
  int idx = blockIdx.x * 256 + threadIdx.x;
  int v = (idx < NNODES) ? deg[idx] : 0;
  #pragma unroll
  for (int m = 32; m >= 1; m >>= 1) v += __shfl_xor(v, m, 64);
  __shared__ int ws[4];
  int lane = threadIdx.x & 63, w = threadIdx.x >> 6;
  if (lane == 0) ws[w] = v;
  __syncthreads();
  if (threadIdx.x == 0) bsum[blockIdx.x] = ws[0] + ws[1] + ws[2] + ws[3];
}

__global__ __launch_bounds__(256) void bscan_k(const int* __restrict__ bsum,
                                               int* __restrict__ bofs) {
  int t = threadIdx.x;
  int v = (t < NBLK) ? bsum[t] : 0;
  int lane = t & 63, w = t >> 6;
  int sc = v;
  #pragma unroll
  for (int off = 1; off < 64; off <<= 1) {
    int u = __shfl_up(sc, off, 64);
    if (lane >= off) sc += u;
  }
  __shared__ int ws[4];
  if (lane == 63) ws[w] = sc;
  __syncthreads();
  int wo = 0;
  for (int i = 0; i < w; ++i) wo += ws[i];
  if (t < NBLK) bofs[t] = wo + sc - v;
}

__global__ __launch_bounds__(256) void csr_offsets_k(const int* __restrict__ deg,
                                                     const int* __restrict__ bofs,
                                                     int* __restrict__ row_start,
                                                     int* __restrict__ cursor) {
  int t = threadIdx.x;
  int idx = blockIdx.x * 256 + t;
  int v = (idx < NNODES) ? deg[idx] : 0;
  int lane = t & 63, w = t >> 6;
  int sc = v;
  #pragma unroll
  for (int off = 1; off < 64; off <<= 1) {
    int u = __shfl_up(sc, off, 64);
    if (lane >= off) sc += u;
  }
  __shared__ int ws[4];
  if (lane == 63) ws[w] = sc;
  __syncthreads();
  int wo = 0;
  for (int i = 0; i < w; ++i) wo += ws[i];
  int excl = bofs[blockIdx.x] + wo + sc - v;
  if (idx < NNODES) {
    row_start[idx] = excl;
    cursor[idx] = excl;
    if (idx == NNODES - 1) row_start[NNODES] = excl + v;
  }
}

__global__ void scales_k(const int* __restrict__ deg, const float* __restrict__ logsum,
                         float* __restrict__ scales) {
  int i = blockIdx.x * blockDim.x + threadIdx.x;
  if (i >= NNODES) return;
  float mean = *logsum / (float)NNODES;
  float sc = logf((float)(deg[i] + 1)) / mean;
  scales[i*3 + 0] = 1.0f;
  scales[i*3 + 1] = sc;
  scales[i*3 + 2] = 1.0f / fmaxf(sc, 0.01f);
}

__global__ void scatter_k(const int* __restrict__ ei, const int* __restrict__ etype,
                          const float* __restrict__ ew, int* __restrict__ cursor,
                          int* __restrict__ s_srt, int* __restrict__ t_srt,
                          float* __restrict__ w_srt) {
  int e = blockIdx.x * blockDim.x + threadIdx.x;
  if (e >= NEDGES) return;
  int d = ei[NEDGES + e];
  int pos = atomicAdd(&cursor[d], 1);
  s_srt[pos] = ei[e];
  t_srt[pos] = etype[e];
  w_srt[pos] = ew[e];
}

// ---------------- W pre-split into GEMM-ready swizzled tiles (R7 layout) ----------------

__global__ void wsplit_k(const float* __restrict__ W, ushort* __restrict__ wt) {
  int id = blockIdx.x * blockDim.x + threadIdx.x;
  if (id >= NLAYERS * KDIM * DIM) return;
  int col = id & 127;
  int k = (id >> 7) % KDIM;
  int l = id / (KDIM * DIM);
  float v = W[(size_t)l * KDIM * DIM + (size_t)k * DIM + col];
  ushort h = bf16_rne(v);
  ushort lo = bf16_rne(v - bf16_f(h));
  int c = k >> 5, kk = k & 31;
  int by = col >> 6, ch = col & 63;
  int tidx = (c < 48) ? ((c & 15) * 3 + (c >> 4)) : c;
  size_t base = (size_t)(((size_t)l * 2 + by) * 52 + tidx) * TILE_US;
  int slot = (kk >> 3) ^ ((ch >> 1) & 3);
  int off = ch * 32 + (slot << 3) + (kk & 7);
  wt[base + off] = h;
  wt[base + 2048 + off] = lo;
}

// ---------------- x -> bf16 hi/lo planes ----------------

__global__ void xsplit_k(const float* __restrict__ x, ushort* __restrict__ xh,
                         ushort* __restrict__ xl) {
  int id = blockIdx.x * blockDim.x + threadIdx.x;
  if (id >= NNODES * 64) return;
  f2 v = *(const f2*)(x + (size_t)id * 2);
  ushort h0 = bf16_rne(v.x), h1 = bf16_rne(v.y);
  ushort l0 = bf16_rne(v.x - bf16_f(h0)), l1 = bf16_rne(v.y - bf16_f(h1));
  ((uint*)xh)[id] = (uint)h0 | ((uint)h1 << 16);
  ((uint*)xl)[id] = (uint)l0 | ((uint)l1 << 16);
}

// ---------------- per-layer aggregation (one wave per destination node) ----------------
// L2-sliced gathers: edges preloaded into lane registers (R9), then iterated once
// per source-node slice (8 slices x 3.2 MB) so that concurrently-running waves all
// gather from the same L2-resident slice of x. Wave-uniform slice test -> no divergence.

__global__ __launch_bounds__(256) void aggregate_k(
    const float* __restrict__ x, const float* __restrict__ x0,
    const float* __restrict__ relw, const int* __restrict__ row_start,
    const int* __restrict__ s_srt, const int* __restrict__ t_srt,
    const float* __restrict__ w_srt,
    ushort* __restrict__ sh, ushort* __restrict__ sl)
{
  int wid = blockIdx.x * 4 + (threadIdx.x >> 6);
  if (wid >= NNODES) return;
  int lane = threadIdx.x & 63;
  int j0 = lane * 2;
  int beg = row_start[wid], end = row_start[wid + 1];
  int deg = end - beg;
  f2 sum = {0.f, 0.f}, sq = {0.f, 0.f};
  f2 mx = {-INFINITY, -INFINITY}, mn = {INFINITY, INFINITY};

  // lane-parallel preload of up to 64 edge records
  int eidx = beg + lane;
  bool va = eidx < end;
  int   sv = va ? s_srt[eidx] : 0;
  int   tv = va ? t_srt[eidx] : 0;
  float wv = va ? w_srt[eidx] : 0.0f;

  int n = (deg < 64) ? deg : 64;
  #pragma unroll 1
  for (int slc = 0; slc < 8; ++slc) {
    int lo = slc * SLICE_N, hi = lo + SLICE_N;   // slice 7 covers the tail
    if (slc == 7) hi = NNODES;
    for (int e = 0; e < n; ++e) {
      int s = __shfl(sv, e, 64);                 // wave-uniform
      if (s < lo || s >= hi) continue;           // uniform branch, no divergence
      int ty = __shfl(tv, e, 64);
      float w = __shfl(wv, e, 64);
      f2 xs = *(const f2*)(x + (size_t)s * DIM + j0);
      f2 rv = *(const f2*)(relw + (size_t)ty * DIM + j0);
      f2 m = xs * rv * w;
      sum += m; sq += m * m;
      mx = fmax2(mx, m); mn = fmin2(mn, m);
    }
  }
  // rare overflow path (deg > 64)
  for (int ee = beg + 64; ee < end; ++ee) {
    int s = s_srt[ee]; int ty = t_srt[ee]; float w = w_srt[ee];
    f2 xs = *(const f2*)(x + (size_t)s * DIM + j0);
    f2 rv = *(const f2*)(relw + (size_t)ty * DIM + j0);
    f2 m = xs * rv * w;
    sum += m; sq += m * m;
    mx = fmax2(mx, m); mn = fmin2(mn, m);
  }

  f2 x0v = *(const f2*)(x0 + (size_t)wid * DIM + j0);
  sum += x0v; sq += x0v * x0v;
  mx = fmax2(mx, x0v); mn = fmin2(mn, x0v);
  float dq = (float)(deg + 1);
  f2 mean = sum / dq;
  f2 sqm = sq / dq;
  f2 var = sqm - mean * mean;
  f2 sd; sd.x = sqrtf(fmaxf(var.x, 1e-6f)); sd.y = sqrtf(fmaxf(var.y, 1e-6f));
  f2 feats[4] = {mean, mx, mn, sd};
  size_t base = (size_t)wid * 512 + j0;
  #pragma unroll
  for (int f = 0; f < 4; ++f) {
    f2 v = feats[f];
    ushort h0 = bf16_rne(v.x), h1 = bf16_rne(v.y);
    ushort l0 = bf16_rne(v.x - bf16_f(h0)), l1 = bf16_rne(v.y - bf16_f(h1));
    *(uint*)(sh + base + f * 128) = (uint)h0 | ((uint)h1 << 16);
    *(uint*)(sl + base + f * 128) = (uint)l0 | ((uint)l1 << 16);
  }
}

// ---------------- scale-folded split-bf16 MFMA GEMM (R7-exact, proven 76.4 us) ----------------

__global__ __launch_bounds__(512, 2) void gemm_mfma_k(
    const ushort* __restrict__ sh, const ushort* __restrict__ sl,
    const ushort* __restrict__ xh, const ushort* __restrict__ xl,
    const float* __restrict__ scales, const ushort* __restrict__ wtl,
    float* __restrict__ Y)
{
  __shared__ ushort As[2 * TILE_US];      // hi [128][32], lo [128][32] (swizzled rows)
  __shared__ ushort Bs[2][3 * TILE_US];   // double-buffered, up to 3 s-tiles
  int t = threadIdx.x;
  int w = t >> 6, lane = t & 63;
  int lr = lane & 15, lk = lane >> 4;
  int wr = w >> 1, wcq = w & 1;
  int row0 = blockIdx.x * 128;
  int by = blockIdx.y;

  // staging role: A row sr (0..127), slot sq
  int sr = t >> 2, sq = t & 3;
  int an = row0 + sr; if (an >= NNODES) an = NNODES - 1;
  int aoff = sr * 32 + ((sq ^ ((sr >> 1) & 3)) << 3);

  f32x4 p0_00, p0_01, p0_10, p0_11;
  f32x4 p1_00, p1_01, p1_10, p1_11;
  f32x4 p2_00, p2_01, p2_10, p2_11;
  p0_00 = p0_01 = p0_10 = p0_11 = (f32x4){0.f,0.f,0.f,0.f};
  p1_00 = p1_01 = p1_10 = p1_11 = (f32x4){0.f,0.f,0.f,0.f};
  p2_00 = p2_01 = p2_10 = p2_11 = (f32x4){0.f,0.f,0.f,0.f};

  bf16x8 rh, rl;
  auto loadA = [&](int cp) {
    const ushort *ph, *pl;
    if (cp < 16) {
      ph = sh + (size_t)an * 512 + cp * 32 + sq * 8;
      pl = sl + (size_t)an * 512 + cp * 32 + sq * 8;
    } else {
      ph = xh + (size_t)an * 128 + (cp - 16) * 32 + sq * 8;
      pl = xl + (size_t)an * 128 + (cp - 16) * 32 + sq * 8;
    }
    rh = *(const bf16x8*)ph;
    rl = *(const bf16x8*)pl;
  };
  auto issueB = [&](int cp, ushort* dst) {
    int tile0 = (cp < 16) ? cp * 3 : cp + 32;
    const char* src = (const char*)(wtl + ((size_t)by * 52 + tile0) * TILE_US);
    char* d = (char*)dst;
    gload_lds16(src + t * 16, d + t * 16);
    if (cp < 16) {
      gload_lds16(src + (512 + t) * 16, d + (512 + t) * 16);
      gload_lds16(src + (1024 + t) * 16, d + (1024 + t) * 16);
    }
  };

  // prologue: stage chunk 0
  issueB(0, Bs[0]);
  loadA(0);
  *(bf16x8*)(As + aoff) = rh;
  *(bf16x8*)(As + TILE_US + aoff) = rl;
  __syncthreads();   // drains B(0) vmcnt + publishes As(0)

  int cur = 0;
  const int ar = wr * 32 + lr;
  const int aswz = ar * 32 + ((lk ^ ((ar >> 1) & 3)) << 3);
  const int br = wcq * 32 + lr;
  const int bswz = br * 32 + ((lk ^ ((br >> 1) & 3)) << 3);

#define MFMA_S(pa, pb, pc, pd, Btile)                                              \
  {                                                                                \
    const ushort* Bb = (Btile) + bswz;                                             \
    bf16x8 bh0 = *(const bf16x8*)(Bb);                                             \
    bf16x8 bl0 = *(const bf16x8*)(Bb + 2048);                                      \
    bf16x8 bh1 = *(const bf16x8*)(Bb + 512);                                       \
    bf16x8 bl1 = *(const bf16x8*)(Bb + 2048 + 512);                                \
    pa = __builtin_amdgcn_mfma_f32_16x16x32_bf16(ah0, bh0, pa, 0,0,0);             \
    pa = __builtin_amdgcn_mfma_f32_16x16x32_bf16(ah0, bl0, pa, 0,0,0);             \
    pa = __builtin_amdgcn_mfma_f32_16x16x32_bf16(al0, bh0, pa, 0,0,0);             \
    pb = __builtin_amdgcn_mfma_f32_16x16x32_bf16(ah0, bh1, pb, 0,0,0);             \
    pb = __builtin_amdgcn_mfma_f32_16x16x32_bf16(ah0, bl1, pb, 0,0,0);             \
    pb = __builtin_amdgcn_mfma_f32_16x16x32_bf16(al0, bh1, pb, 0,0,0);             \
    pc = __builtin_amdgcn_mfma_f32_16x16x32_bf16(ah1, bh0, pc, 0,0,0);             \
    pc = __builtin_amdgcn_mfma_f32_16x16x32_bf16(ah1, bl0, pc, 0,0,0);             \
    pc = __builtin_amdgcn_mfma_f32_16x16x32_bf16(al1, bh0, pc, 0,0,0);             \
    pd = __builtin_amdgcn_mfma_f32_16x16x32_bf16(ah1, bh1, pd, 0,0,0);             \
    pd = __builtin_amdgcn_mfma_f32_16x16x32_bf16(ah1, bl1, pd, 0,0,0);             \
    pd = __builtin_amdgcn_mfma_f32_16x16x32_bf16(al1, bh1, pd, 0,0,0);             \
  }

  for (int cp = 0; cp < 20; ++cp) {
    // issue next chunk's loads FIRST (overlap with compute below)
    if (cp < 19) {
      issueB(cp + 1, Bs[cur ^ 1]);
      loadA(cp + 1);
    }
    // ---- compute from As, Bs[cur] ----
    const ushort* Ab = As + aswz;
    bf16x8 ah0 = *(const bf16x8*)(Ab);
    bf16x8 al0 = *(const bf16x8*)(Ab + TILE_US);
    bf16x8 ah1 = *(const bf16x8*)(Ab + 512);
    bf16x8 al1 = *(const bf16x8*)(Ab + TILE_US + 512);
    const ushort* Bcur = Bs[cur];
    if (cp < 16) {
      MFMA_S(p0_00, p0_01, p0_10, p0_11, Bcur);
      MFMA_S(p1_00, p1_01, p1_10, p1_11, Bcur + TILE_US);
      MFMA_S(p2_00, p2_01, p2_10, p2_11, Bcur + 2 * TILE_US);
    } else {
      MFMA_S(p0_00, p0_01, p0_10, p0_11, Bcur);
    }
    __syncthreads();   // drains B(cp+1) (landed during compute); As/Bs reads done
    if (cp < 19) {
      *(bf16x8*)(As + aoff) = rh;              // A(cp+1) -> LDS
      *(bf16x8*)(As + TILE_US + aoff) = rl;
    }
    cur ^= 1;
    __syncthreads();   // publish As(cp+1); vmcnt already drained -> cheap
  }
#undef MFMA_S

  // ---- epilogue: fold scales, write Y ----
  int colg = by * 64 + wcq * 32;
  f32x4 q0[2][2] = {{p0_00, p0_01}, {p0_10, p0_11}};
  f32x4 q1[2][2] = {{p1_00, p1_01}, {p1_10, p1_11}};
  f32x4 q2[2][2] = {{p2_00, p2_01}, {p2_10, p2_11}};
  #pragma unroll
  for (int fr = 0; fr < 2; ++fr) {
    int rbase = row0 + wr * 32 + fr * 16 + lk * 4;
    #pragma unroll
    for (int q = 0; q < 4; ++q) {
      int r = rbase + q;
      int rc = (r < NNODES) ? r : (NNODES - 1);
      float s1 = scales[rc * 3 + 1];
      float s2 = scales[rc * 3 + 2];
      if (r < NNODES) {
        #pragma unroll
        for (int fc = 0; fc < 2; ++fc) {
          float o = q0[fr][fc][q] + s1 * q1[fr][fc][q] + s2 * q2[fr][fc][q];
          Y[(size_t)r * DIM + colg + fc * 16 + lr] = o;
        }
      }
    }
  }
}

// ---------------- bias + LN + relu + residual; also emit x hi/lo planes ----------------

__global__ __launch_bounds__(256) void ln_k(
    const float* __restrict__ Y, const float* __restrict__ bias,
    const float* __restrict__ gam, const float* __restrict__ bet,
    float* __restrict__ x, ushort* __restrict__ xh, ushort* __restrict__ xl)
{
  int wid = blockIdx.x * 4 + (threadIdx.x >> 6);
  if (wid >= NNODES) return;
  int lane = threadIdx.x & 63;
  int j0 = lane * 2;
  f2 v = *(const f2*)(Y + (size_t)wid * DIM + j0);
  f2 b = *(const f2*)(bias + j0);
  v += b;
  float s = v.x + v.y;
  float q = v.x * v.x + v.y * v.y;
  #pragma unroll
  for (int m = 1; m < 64; m <<= 1) { s += __shfl_xor(s, m, 64); q += __shfl_xor(q, m, 64); }
  float mu = s * (1.0f / 128.0f);
  float var = q * (1.0f / 128.0f) - mu * mu;
  float rstd = rsqrtf(var + 1e-5f);
  f2 g = *(const f2*)(gam + j0);
  f2 be = *(const f2*)(bet + j0);
  f2 o = (v - mu) * rstd * g + be;
  o.x = fmaxf(o.x, 0.f); o.y = fmaxf(o.y, 0.f);
  float* xp = x + (size_t)wid * DIM + j0;
  f2 xr = *(const f2*)xp;
  f2 res = o + xr;
  *(f2*)xp = res;
  ushort h0 = bf16_rne(res.x), h1 = bf16_rne(res.y);
  ushort l0 = bf16_rne(res.x - bf16_f(h0)), l1 = bf16_rne(res.y - bf16_f(h1));
  *(uint*)(xh + (size_t)wid * 128 + j0) = (uint)h0 | ((uint)h1 << 16);
  *(uint*)(xl + (size_t)wid * 128 + j0) = (uint)l0 | ((uint)l1 << 16);
}

// ---------------- distmult scoring ----------------

__global__ __launch_bounds__(256) void score_k(
    const float* __restrict__ x, const float* __restrict__ qw,
    const int* __restrict__ src, const int* __restrict__ rel,
    const int* __restrict__ dst, float* __restrict__ out)
{
  int wid = blockIdx.x * 4 + (threadIdx.x >> 6);
  if (wid >= NTRIPLES) return;
  int lane = threadIdx.x & 63;
  int j0 = lane * 2;
  int s = src[wid], r = rel[wid], d = dst[wid];
  f2 xs = *(const f2*)(x  + (size_t)s * DIM + j0);
  f2 q  = *(const f2*)(qw + (size_t)r * DIM + j0);
  f2 xd = *(const f2*)(x  + (size_t)d * DIM + j0);
  float p = xs.x*q.x*xd.x + xs.y*q.y*xd.y;
  #pragma unroll
  for (int m = 32; m >= 1; m >>= 1) p += __shfl_xor(p, m, 64);
  if (lane == 0) out[wid] = p;
}

// ---------------- launch ----------------

extern "C" void kernel_launch(void* const* d_in, const int* in_sizes, int n_in,
                              void* d_out, int out_size, void* d_ws, size_t ws_size,
                              hipStream_t stream) {
  const float* x0    = (const float*)d_in[0];
  const int*   ei    = (const int*)d_in[1];
  const int*   etyp  = (const int*)d_in[2];
  const float* ew    = (const float*)d_in[3];
  const float* rel_w = (const float*)d_in[4];
  const float* lin_w = (const float*)d_in[5];
  const float* lin_b = (const float*)d_in[6];
  const float* ln_g  = (const float*)d_in[7];
  const float* lnb   = (const float*)d_in[8];
  const float* qw    = (const float*)d_in[9];
  const int*   srcq  = (const int*)d_in[10];
  const int*   relq  = (const int*)d_in[11];
  const int*   dstq  = (const int*)d_in[12];
  float* out = (float*)d_out;

  char* ws = (char*)d_ws;
  size_t off = 0;
  auto alloc = [&](size_t bytes) -> void* {
    void* p = ws + off; off = (off + bytes + 255) & ~(size_t)255; return p;
  };
  int*    deg       = (int*)alloc((size_t)NNODES * 4);
  int*    row_start = (int*)alloc((size_t)(NNODES + 1) * 4);
  int*    cursor    = (int*)alloc((size_t)NNODES * 4);
  int*    bsum      = (int*)alloc((size_t)(NBLK + 1) * 4);
  int*    bofs      = (int*)alloc((size_t)(NBLK + 1) * 4);
  int*    s_srt     = (int*)alloc((size_t)NEDGES * 4);
  int*    t_srt     = (int*)alloc((size_t)NEDGES * 4);
  float*  w_srt     = (float*)alloc((size_t)NEDGES * 4);
  float*  scales    = (float*)alloc((size_t)NNODES * 3 * 4);
  float*  logsum    = (float*)alloc(256);
  ushort* stats_hi  = (ushort*)alloc((size_t)NNODES * 512 * 2);
  ushort* stats_lo  = (ushort*)alloc((size_t)NNODES * 512 * 2);
  float*  xbuf      = (float*)alloc((size_t)NNODES * DIM * 4);
  ushort* xhi       = (ushort*)alloc((size_t)NNODES * DIM * 2);
  ushort* xlo       = (ushort*)alloc((size_t)NNODES * DIM * 2);
  float*  Ybuf      = (float*)alloc((size_t)NNODES * DIM * 4);
  ushort* wtbuf     = (ushort*)alloc((size_t)NLAYERS * 2 * 52 * TILE_US * 2);

  hipMemsetAsync(deg, 0, (size_t)NNODES * 4, stream);
  hipMemsetAsync(logsum, 0, 4, stream);
  deg_hist_k<<<(NEDGES + 255) / 256, 256, 0, stream>>>(ei, deg);
  logsum_k<<<(NNODES + 255) / 256, 256, 0, stream>>>(deg, logsum);
  blocksum_k<<<NBLK, 256, 0, stream>>>(deg, bsum);
  bscan_k<<<1, 256, 0, stream>>>(bsum, bofs);
  csr_offsets_k<<<NBLK, 256, 0, stream>>>(deg, bofs, row_start, cursor);
  scales_k<<<(NNODES + 255) / 256, 256, 0, stream>>>(deg, logsum, scales);
  scatter_k<<<(NEDGES + 255) / 256, 256, 0, stream>>>(ei, etyp, ew, cursor, s_srt, t_srt, w_srt);
  wsplit_k<<<(NLAYERS * KDIM * DIM + 255) / 256, 256, 0, stream>>>(lin_w, wtbuf);
  hipMemcpyAsync(xbuf, x0, (size_t)NNODES * DIM * 4, hipMemcpyDeviceToDevice, stream);
  xsplit_k<<<(NNODES * 64 + 255) / 256, 256, 0, stream>>>(x0, xhi, xlo);

  for (int l = 0; l < NLAYERS; ++l) {
    aggregate_k<<<(NNODES + 3) / 4, 256, 0, stream>>>(
        xbuf, x0, rel_w + (size_t)l * NREL * DIM, row_start, s_srt, t_srt, w_srt,
        stats_hi, stats_lo);
    dim3 gg((NNODES + 127) / 128, 2);
    gemm_mfma_k<<<gg, 512, 0, stream>>>(
        stats_hi, stats_lo, xhi, xlo, scales,
        wtbuf + (size_t)l * 2 * 52 * TILE_US, Ybuf);
    ln_k<<<(NNODES + 3) / 4, 256, 0, stream>>>(
        Ybuf, lin_b + (size_t)l * DIM, ln_g + (size_t)l * DIM, lnb + (size_t)l * DIM,
        xbuf, xhi, xlo);
  }
  score_k<<<(NTRIPLES + 3) / 4, 256, 0, stream>>>(xbuf, qw, srcq, relq, dstq, out);
}

// Round 14
// 600.519 us; speedup vs baseline: 3.6863x; 1.4823x over previous
//
#include <hip/hip_runtime.h>
#include <math.h>

#define NNODES 50000
#define NEDGES 500000
#define DIM 128
#define NREL 51
#define NLAYERS 4
#define NTRIPLES (1024*32)
#define KDIM 1664     // 13*128
#define TILE_US 4096  // one B tile = 2 planes * 64 rows * 32 ushorts (swizzled 64B rows)
#define NBLK 196      // ceil(NNODES/256)

typedef float f2 __attribute__((ext_vector_type(2)));
typedef float f32x4 __attribute__((ext_vector_type(4)));
typedef short bf16x8 __attribute__((ext_vector_type(8)));

static __device__ __forceinline__ ushort bf16_rne(float v) {
  unsigned u = __float_as_uint(v);
  unsigned r = (u + 0x7fffu + ((u >> 16) & 1u)) >> 16;
  return (ushort)r;
}
static __device__ __forceinline__ float bf16_f(ushort h) {
  return __uint_as_float(((unsigned)h) << 16);
}
static __device__ __forceinline__ f2 fmax2(f2 a, f2 b) { f2 r; r.x = fmaxf(a.x,b.x); r.y = fmaxf(a.y,b.y); return r; }
static __device__ __forceinline__ f2 fmin2(f2 a, f2 b) { f2 r; r.x = fminf(a.x,b.x); r.y = fminf(a.y,b.y); return r; }

// async global->LDS, 16B per lane; LDS dest = wave-uniform base + lane*16 (linear layout only)
static __device__ __forceinline__ void gload_lds16(const void* g, void* l) {
  __builtin_amdgcn_global_load_lds(
      (const __attribute__((address_space(1))) unsigned int*)g,
      (__attribute__((address_space(3))) unsigned int*)l,
      16, 0, 0);
}

// ---------------- graph prep ----------------

__global__ void deg_hist_k(const int* __restrict__ ei, int* __restrict__ deg) {
  int e = blockIdx.x * blockDim.x + threadIdx.x;
  if (e < NEDGES) atomicAdd(&deg[ei[NEDGES + e]], 1);
}

__global__ void logsum_k(const int* __restrict__ deg, float* __restrict__ acc) {
  int i = blockIdx.x * blockDim.x + threadIdx.x;
  float v = (i < NNODES) ? logf((float)(deg[i] + 1)) : 0.0f;
  #pragma unroll
  for (int m = 32; m >= 1; m >>= 1) v += __shfl_xor(v, m, 64);
  __shared__ float ws[4];
  int lane = threadIdx.x & 63, w = threadIdx.x >> 6;
  if (lane == 0) ws[w] = v;
  __syncthreads();
  if (threadIdx.x == 0) atomicAdd(acc, ws[0] + ws[1] + ws[2] + ws[3]);
}

// ---- hierarchical scan: blocksum -> bscan -> csr_offsets ----

__global__ __launch_bounds__(256) void blocksum_k(const int* __restrict__ deg,
                                                  int* __restrict__ bsum) {
  int idx = blockIdx.x * 256 + threadIdx.x;
  int v = (idx < NNODES) ? deg[idx] : 0;
  #pragma unroll
  for (int m = 32; m >= 1; m >>= 1) v += __shfl_xor(v, m, 64);
  __shared__ int ws[4];
  int lane = threadIdx.x & 63, w = threadIdx.x >> 6;
  if (lane == 0) ws[w] = v;
  __syncthreads();
  if (threadIdx.x == 0) bsum[blockIdx.x] = ws[0] + ws[1] + ws[2] + ws[3];
}

__global__ __launch_bounds__(256) void bscan_k(const int* __restrict__ bsum,
                                               int* __restrict__ bofs) {
  int t = threadIdx.x;
  int v = (t < NBLK) ? bsum[t] : 0;
  int lane = t & 63, w = t >> 6;
  int sc = v;
  #pragma unroll
  for (int off = 1; off < 64; off <<= 1) {
    int u = __shfl_up(sc, off, 64);
    if (lane >= off) sc += u;
  }
  __shared__ int ws[4];
  if (lane == 63) ws[w] = sc;
  __syncthreads();
  int wo = 0;
  for (int i = 0; i < w; ++i) wo += ws[i];
  if (t < NBLK) bofs[t] = wo + sc - v;
}

__global__ __launch_bounds__(256) void csr_offsets_k(const int* __restrict__ deg,
                                                     const int* __restrict__ bofs,
                                                     int* __restrict__ row_start,
                                                     int* __restrict__ cursor) {
  int t = threadIdx.x;
  int idx = blockIdx.x * 256 + t;
  int v = (idx < NNODES) ? deg[idx] : 0;
  int lane = t & 63, w = t >> 6;
  int sc = v;
  #pragma unroll
  for (int off = 1; off < 64; off <<= 1) {
    int u = __shfl_up(sc, off, 64);
    if (lane >= off) sc += u;
  }
  __shared__ int ws[4];
  if (lane == 63) ws[w] = sc;
  __syncthreads();
  int wo = 0;
  for (int i = 0; i < w; ++i) wo += ws[i];
  int excl = bofs[blockIdx.x] + wo + sc - v;
  if (idx < NNODES) {
    row_start[idx] = excl;
    cursor[idx] = excl;
    if (idx == NNODES - 1) row_start[NNODES] = excl + v;
  }
}

__global__ void scales_k(const int* __restrict__ deg, const float* __restrict__ logsum,
                         float* __restrict__ scales) {
  int i = blockIdx.x * blockDim.x + threadIdx.x;
  if (i >= NNODES) return;
  float mean = *logsum / (float)NNODES;
  float sc = logf((float)(deg[i] + 1)) / mean;
  scales[i*3 + 0] = 1.0f;
  scales[i*3 + 1] = sc;
  scales[i*3 + 2] = 1.0f / fmaxf(sc, 0.01f);
}

__global__ void scatter_k(const int* __restrict__ ei, const int* __restrict__ etype,
                          const float* __restrict__ ew, int* __restrict__ cursor,
                          int* __restrict__ s_srt, int* __restrict__ t_srt,
                          float* __restrict__ w_srt) {
  int e = blockIdx.x * blockDim.x + threadIdx.x;
  if (e >= NEDGES) return;
  int d = ei[NEDGES + e];
  int pos = atomicAdd(&cursor[d], 1);
  s_srt[pos] = ei[e];
  t_srt[pos] = etype[e];
  w_srt[pos] = ew[e];
}

// ---------------- W pre-split into GEMM-ready swizzled tiles (R7 layout) ----------------

__global__ void wsplit_k(const float* __restrict__ W, ushort* __restrict__ wt) {
  int id = blockIdx.x * blockDim.x + threadIdx.x;
  if (id >= NLAYERS * KDIM * DIM) return;
  int col = id & 127;
  int k = (id >> 7) % KDIM;
  int l = id / (KDIM * DIM);
  float v = W[(size_t)l * KDIM * DIM + (size_t)k * DIM + col];
  ushort h = bf16_rne(v);
  ushort lo = bf16_rne(v - bf16_f(h));
  int c = k >> 5, kk = k & 31;
  int by = col >> 6, ch = col & 63;
  int tidx = (c < 48) ? ((c & 15) * 3 + (c >> 4)) : c;
  size_t base = (size_t)(((size_t)l * 2 + by) * 52 + tidx) * TILE_US;
  int slot = (kk >> 3) ^ ((ch >> 1) & 3);
  int off = ch * 32 + (slot << 3) + (kk & 7);
  wt[base + off] = h;
  wt[base + 2048 + off] = lo;
}

// ---------------- x -> bf16 hi/lo planes ----------------

__global__ void xsplit_k(const float* __restrict__ x, ushort* __restrict__ xh,
                         ushort* __restrict__ xl) {
  int id = blockIdx.x * blockDim.x + threadIdx.x;
  if (id >= NNODES * 64) return;
  f2 v = *(const f2*)(x + (size_t)id * 2);
  ushort h0 = bf16_rne(v.x), h1 = bf16_rne(v.y);
  ushort l0 = bf16_rne(v.x - bf16_f(h0)), l1 = bf16_rne(v.y - bf16_f(h1));
  ((uint*)xh)[id] = (uint)h0 | ((uint)h1 << 16);
  ((uint*)xl)[id] = (uint)l0 | ((uint)l1 << 16);
}

// ---------------- per-layer aggregation (one wave per destination node) ----------------
// R9 structure (lane-parallel edge preload + shuffle broadcast); stats emitted as
// bf16 HI plane only (lo dropped: error ~2^-9 relative through W, see R14 analysis).

__global__ __launch_bounds__(256) void aggregate_k(
    const float* __restrict__ x, const float* __restrict__ x0,
    const float* __restrict__ relw, const int* __restrict__ row_start,
    const int* __restrict__ s_srt, const int* __restrict__ t_srt,
    const float* __restrict__ w_srt,
    ushort* __restrict__ sh)
{
  int wid = blockIdx.x * 4 + (threadIdx.x >> 6);
  if (wid >= NNODES) return;
  int lane = threadIdx.x & 63;
  int j0 = lane * 2;
  int beg = row_start[wid], end = row_start[wid + 1];
  int deg = end - beg;
  f2 sum = {0.f, 0.f}, sq = {0.f, 0.f};
  f2 mx = {-INFINITY, -INFINITY}, mn = {INFINITY, INFINITY};

  // lane-parallel preload of up to 64 edge records
  int eidx = beg + lane;
  bool va = eidx < end;
  int   sv = va ? s_srt[eidx] : 0;
  int   tv = va ? t_srt[eidx] : 0;
  float wv = va ? w_srt[eidx] : 0.0f;

  int n = (deg < 64) ? deg : 64;
  int e = 0;
  for (; e + 4 <= n; e += 4) {
    int s0 = __shfl(sv, e, 64),     s1 = __shfl(sv, e + 1, 64);
    int s2 = __shfl(sv, e + 2, 64), s3 = __shfl(sv, e + 3, 64);
    int t0 = __shfl(tv, e, 64),     t1 = __shfl(tv, e + 1, 64);
    int t2 = __shfl(tv, e + 2, 64), t3 = __shfl(tv, e + 3, 64);
    float w0 = __shfl(wv, e, 64),     w1 = __shfl(wv, e + 1, 64);
    float w2 = __shfl(wv, e + 2, 64), w3 = __shfl(wv, e + 3, 64);
    f2 xa = *(const f2*)(x + (size_t)s0 * DIM + j0);
    f2 xb = *(const f2*)(x + (size_t)s1 * DIM + j0);
    f2 xc = *(const f2*)(x + (size_t)s2 * DIM + j0);
    f2 xd = *(const f2*)(x + (size_t)s3 * DIM + j0);
    f2 ra = *(const f2*)(relw + (size_t)t0 * DIM + j0);
    f2 rb = *(const f2*)(relw + (size_t)t1 * DIM + j0);
    f2 rc = *(const f2*)(relw + (size_t)t2 * DIM + j0);
    f2 rd = *(const f2*)(relw + (size_t)t3 * DIM + j0);
    f2 m0 = xa * ra * w0;
    f2 m1 = xb * rb * w1;
    f2 m2 = xc * rc * w2;
    f2 m3 = xd * rd * w3;
    sum += m0 + m1 + m2 + m3;
    sq += m0*m0 + m1*m1 + m2*m2 + m3*m3;
    mx = fmax2(fmax2(fmax2(mx, m0), fmax2(m1, m2)), m3);
    mn = fmin2(fmin2(fmin2(mn, m0), fmin2(m1, m2)), m3);
  }
  for (; e < n; ++e) {
    int s = __shfl(sv, e, 64);
    int ty = __shfl(tv, e, 64);
    float w = __shfl(wv, e, 64);
    f2 xs = *(const f2*)(x + (size_t)s * DIM + j0);
    f2 rv = *(const f2*)(relw + (size_t)ty * DIM + j0);
    f2 m = xs * rv * w;
    sum += m; sq += m * m;
    mx = fmax2(mx, m); mn = fmin2(mn, m);
  }
  // rare overflow path (deg > 64)
  for (int ee = beg + 64; ee < end; ++ee) {
    int s = s_srt[ee]; int ty = t_srt[ee]; float w = w_srt[ee];
    f2 xs = *(const f2*)(x + (size_t)s * DIM + j0);
    f2 rv = *(const f2*)(relw + (size_t)ty * DIM + j0);
    f2 m = xs * rv * w;
    sum += m; sq += m * m;
    mx = fmax2(mx, m); mn = fmin2(mn, m);
  }

  f2 x0v = *(const f2*)(x0 + (size_t)wid * DIM + j0);
  sum += x0v; sq += x0v * x0v;
  mx = fmax2(mx, x0v); mn = fmin2(mn, x0v);
  float dq = (float)(deg + 1);
  f2 mean = sum / dq;
  f2 sqm = sq / dq;
  f2 var = sqm - mean * mean;
  f2 sd; sd.x = sqrtf(fmaxf(var.x, 1e-6f)); sd.y = sqrtf(fmaxf(var.y, 1e-6f));
  f2 feats[4] = {mean, mx, mn, sd};
  size_t base = (size_t)wid * 512 + j0;
  #pragma unroll
  for (int f = 0; f < 4; ++f) {
    f2 v = feats[f];
    ushort h0 = bf16_rne(v.x), h1 = bf16_rne(v.y);
    *(uint*)(sh + base + f * 128) = (uint)h0 | ((uint)h1 << 16);
  }
}

// ---------------- scale-folded split-bf16 MFMA GEMM (R7 skeleton) ----------------
// Stat chunks (cp<16): A = bf16-hi only -> 2-term MFMA (ah*bh + ah*bl), 24 MFMA/chunk.
// x chunks (cp>=16): A split hi/lo -> 3-term (residual path stays high precision).

__global__ __launch_bounds__(512, 2) void gemm_mfma_k(
    const ushort* __restrict__ sh,
    const ushort* __restrict__ xh, const ushort* __restrict__ xl,
    const float* __restrict__ scales, const ushort* __restrict__ wtl,
    float* __restrict__ Y)
{
  __shared__ ushort As[2 * TILE_US];      // hi [128][32]; lo [128][32] (x chunks only)
  __shared__ ushort Bs[2][3 * TILE_US];   // double-buffered, up to 3 s-tiles
  int t = threadIdx.x;
  int w = t >> 6, lane = t & 63;
  int lr = lane & 15, lk = lane >> 4;
  int wr = w >> 1, wcq = w & 1;
  int row0 = blockIdx.x * 128;
  int by = blockIdx.y;

  // staging role: A row sr (0..127), slot sq
  int sr = t >> 2, sq = t & 3;
  int an = row0 + sr; if (an >= NNODES) an = NNODES - 1;
  int aoff = sr * 32 + ((sq ^ ((sr >> 1) & 3)) << 3);

  f32x4 p0_00, p0_01, p0_10, p0_11;
  f32x4 p1_00, p1_01, p1_10, p1_11;
  f32x4 p2_00, p2_01, p2_10, p2_11;
  p0_00 = p0_01 = p0_10 = p0_11 = (f32x4){0.f,0.f,0.f,0.f};
  p1_00 = p1_01 = p1_10 = p1_11 = (f32x4){0.f,0.f,0.f,0.f};
  p2_00 = p2_01 = p2_10 = p2_11 = (f32x4){0.f,0.f,0.f,0.f};

  bf16x8 rh, rl;
  auto loadA = [&](int cp) {
    if (cp < 16) {
      rh = *(const bf16x8*)(sh + (size_t)an * 512 + cp * 32 + sq * 8);
    } else {
      rh = *(const bf16x8*)(xh + (size_t)an * 128 + (cp - 16) * 32 + sq * 8);
      rl = *(const bf16x8*)(xl + (size_t)an * 128 + (cp - 16) * 32 + sq * 8);
    }
  };
  auto issueB = [&](int cp, ushort* dst) {
    int tile0 = (cp < 16) ? cp * 3 : cp + 32;
    const char* src = (const char*)(wtl + ((size_t)by * 52 + tile0) * TILE_US);
    char* d = (char*)dst;
    gload_lds16(src + t * 16, d + t * 16);
    if (cp < 16) {
      gload_lds16(src + (512 + t) * 16, d + (512 + t) * 16);
      gload_lds16(src + (1024 + t) * 16, d + (1024 + t) * 16);
    }
  };

  // prologue: stage chunk 0
  issueB(0, Bs[0]);
  loadA(0);
  *(bf16x8*)(As + aoff) = rh;
  __syncthreads();   // drains B(0) vmcnt + publishes As(0)

  int cur = 0;
  const int ar = wr * 32 + lr;
  const int aswz = ar * 32 + ((lk ^ ((ar >> 1) & 3)) << 3);
  const int br = wcq * 32 + lr;
  const int bswz = br * 32 + ((lk ^ ((br >> 1) & 3)) << 3);

#define LOADB(Btile)                                                               \
    const ushort* Bb = (Btile) + bswz;                                             \
    bf16x8 bh0 = *(const bf16x8*)(Bb);                                             \
    bf16x8 bl0 = *(const bf16x8*)(Bb + 2048);                                      \
    bf16x8 bh1 = *(const bf16x8*)(Bb + 512);                                       \
    bf16x8 bl1 = *(const bf16x8*)(Bb + 2048 + 512);

#define MFMA_S2(pa, pb, pc, pd, Btile)                                             \
  {                                                                                \
    LOADB(Btile)                                                                   \
    pa = __builtin_amdgcn_mfma_f32_16x16x32_bf16(ah0, bh0, pa, 0,0,0);             \
    pa = __builtin_amdgcn_mfma_f32_16x16x32_bf16(ah0, bl0, pa, 0,0,0);             \
    pb = __builtin_amdgcn_mfma_f32_16x16x32_bf16(ah0, bh1, pb, 0,0,0);             \
    pb = __builtin_amdgcn_mfma_f32_16x16x32_bf16(ah0, bl1, pb, 0,0,0);             \
    pc = __builtin_amdgcn_mfma_f32_16x16x32_bf16(ah1, bh0, pc, 0,0,0);             \
    pc = __builtin_amdgcn_mfma_f32_16x16x32_bf16(ah1, bl0, pc, 0,0,0);             \
    pd = __builtin_amdgcn_mfma_f32_16x16x32_bf16(ah1, bh1, pd, 0,0,0);             \
    pd = __builtin_amdgcn_mfma_f32_16x16x32_bf16(ah1, bl1, pd, 0,0,0);             \
  }

#define MFMA_S3(pa, pb, pc, pd, Btile)                                             \
  {                                                                                \
    LOADB(Btile)                                                                   \
    pa = __builtin_amdgcn_mfma_f32_16x16x32_bf16(ah0, bh0, pa, 0,0,0);             \
    pa = __builtin_amdgcn_mfma_f32_16x16x32_bf16(ah0, bl0, pa, 0,0,0);             \
    pa = __builtin_amdgcn_mfma_f32_16x16x32_bf16(al0, bh0, pa, 0,0,0);             \
    pb = __builtin_amdgcn_mfma_f32_16x16x32_bf16(ah0, bh1, pb, 0,0,0);             \
    pb = __builtin_amdgcn_mfma_f32_16x16x32_bf16(ah0, bl1, pb, 0,0,0);             \
    pb = __builtin_amdgcn_mfma_f32_16x16x32_bf16(al0, bh1, pb, 0,0,0);             \
    pc = __builtin_amdgcn_mfma_f32_16x16x32_bf16(ah1, bh0, pc, 0,0,0);             \
    pc = __builtin_amdgcn_mfma_f32_16x16x32_bf16(ah1, bl0, pc, 0,0,0);             \
    pc = __builtin_amdgcn_mfma_f32_16x16x32_bf16(al1, bh0, pc, 0,0,0);             \
    pd = __builtin_amdgcn_mfma_f32_16x16x32_bf16(ah1, bh1, pd, 0,0,0);             \
    pd = __builtin_amdgcn_mfma_f32_16x16x32_bf16(ah1, bl1, pd, 0,0,0);             \
    pd = __builtin_amdgcn_mfma_f32_16x16x32_bf16(al1, bh1, pd, 0,0,0);             \
  }

  for (int cp = 0; cp < 20; ++cp) {
    // issue next chunk's loads FIRST (overlap with compute below)
    if (cp < 19) {
      issueB(cp + 1, Bs[cur ^ 1]);
      loadA(cp + 1);
    }
    // ---- compute from As, Bs[cur] ----
    const ushort* Ab = As + aswz;
    const ushort* Bcur = Bs[cur];
    if (cp < 16) {
      bf16x8 ah0 = *(const bf16x8*)(Ab);
      bf16x8 ah1 = *(const bf16x8*)(Ab + 512);
      MFMA_S2(p0_00, p0_01, p0_10, p0_11, Bcur);
      MFMA_S2(p1_00, p1_01, p1_10, p1_11, Bcur + TILE_US);
      MFMA_S2(p2_00, p2_01, p2_10, p2_11, Bcur + 2 * TILE_US);
    } else {
      bf16x8 ah0 = *(const bf16x8*)(Ab);
      bf16x8 al0 = *(const bf16x8*)(Ab + TILE_US);
      bf16x8 ah1 = *(const bf16x8*)(Ab + 512);
      bf16x8 al1 = *(const bf16x8*)(Ab + TILE_US + 512);
      MFMA_S3(p0_00, p0_01, p0_10, p0_11, Bcur);
    }
    __syncthreads();   // drains B(cp+1) (landed during compute); As/Bs reads done
    if (cp < 19) {
      *(bf16x8*)(As + aoff) = rh;                           // A(cp+1) hi -> LDS
      if (cp + 1 >= 16) *(bf16x8*)(As + TILE_US + aoff) = rl;  // lo only for x chunks
    }
    cur ^= 1;
    __syncthreads();   // publish As(cp+1); vmcnt already drained -> cheap
  }
#undef MFMA_S2
#undef MFMA_S3
#undef LOADB

  // ---- epilogue: fold scales, write Y ----
  int colg = by * 64 + wcq * 32;
  f32x4 q0[2][2] = {{p0_00, p0_01}, {p0_10, p0_11}};
  f32x4 q1[2][2] = {{p1_00, p1_01}, {p1_10, p1_11}};
  f32x4 q2[2][2] = {{p2_00, p2_01}, {p2_10, p2_11}};
  #pragma unroll
  for (int fr = 0; fr < 2; ++fr) {
    int rbase = row0 + wr * 32 + fr * 16 + lk * 4;
    #pragma unroll
    for (int q = 0; q < 4; ++q) {
      int r = rbase + q;
      int rc = (r < NNODES) ? r : (NNODES - 1);
      float s1 = scales[rc * 3 + 1];
      float s2 = scales[rc * 3 + 2];
      if (r < NNODES) {
        #pragma unroll
        for (int fc = 0; fc < 2; ++fc) {
          float o = q0[fr][fc][q] + s1 * q1[fr][fc][q] + s2 * q2[fr][fc][q];
          Y[(size_t)r * DIM + colg + fc * 16 + lr] = o;
        }
      }
    }
  }
}

// ---------------- bias + LN + relu + residual; also emit x hi/lo planes ----------------

__global__ __launch_bounds__(256) void ln_k(
    const float* __restrict__ Y, const float* __restrict__ bias,
    const float* __restrict__ gam, const float* __restrict__ bet,
    float* __restrict__ x, ushort* __restrict__ xh, ushort* __restrict__ xl)
{
  int wid = blockIdx.x * 4 + (threadIdx.x >> 6);
  if (wid >= NNODES) return;
  int lane = threadIdx.x & 63;
  int j0 = lane * 2;
  f2 v = *(const f2*)(Y + (size_t)wid * DIM + j0);
  f2 b = *(const f2*)(bias + j0);
  v += b;
  float s = v.x + v.y;
  float q = v.x * v.x + v.y * v.y;
  #pragma unroll
  for (int m = 1; m < 64; m <<= 1) { s += __shfl_xor(s, m, 64); q += __shfl_xor(q, m, 64); }
  float mu = s * (1.0f / 128.0f);
  float var = q * (1.0f / 128.0f) - mu * mu;
  float rstd = rsqrtf(var + 1e-5f);
  f2 g = *(const f2*)(gam + j0);
  f2 be = *(const f2*)(bet + j0);
  f2 o = (v - mu) * rstd * g + be;
  o.x = fmaxf(o.x, 0.f); o.y = fmaxf(o.y, 0.f);
  float* xp = x + (size_t)wid * DIM + j0;
  f2 xr = *(const f2*)xp;
  f2 res = o + xr;
  *(f2*)xp = res;
  ushort h0 = bf16_rne(res.x), h1 = bf16_rne(res.y);
  ushort l0 = bf16_rne(res.x - bf16_f(h0)), l1 = bf16_rne(res.y - bf16_f(h1));
  *(uint*)(xh + (size_t)wid * 128 + j0) = (uint)h0 | ((uint)h1 << 16);
  *(uint*)(xl + (size_t)wid * 128 + j0) = (uint)l0 | ((uint)l1 << 16);
}

// ---------------- distmult scoring ----------------

__global__ __launch_bounds__(256) void score_k(
    const float* __restrict__ x, const float* __restrict__ qw,
    const int* __restrict__ src, const int* __restrict__ rel,
    const int* __restrict__ dst, float* __restrict__ out)
{
  int wid = blockIdx.x * 4 + (threadIdx.x >> 6);
  if (wid >= NTRIPLES) return;
  int lane = threadIdx.x & 63;
  int j0 = lane * 2;
  int s = src[wid], r = rel[wid], d = dst[wid];
  f2 xs = *(const f2*)(x  + (size_t)s * DIM + j0);
  f2 q  = *(const f2*)(qw + (size_t)r * DIM + j0);
  f2 xd = *(const f2*)(x  + (size_t)d * DIM + j0);
  float p = xs.x*q.x*xd.x + xs.y*q.y*xd.y;
  #pragma unroll
  for (int m = 32; m >= 1; m >>= 1) p += __shfl_xor(p, m, 64);
  if (lane == 0) out[wid] = p;
}

// ---------------- launch ----------------

extern "C" void kernel_launch(void* const* d_in, const int* in_sizes, int n_in,
                              void* d_out, int out_size, void* d_ws, size_t ws_size,
                              hipStream_t stream) {
  const float* x0    = (const float*)d_in[0];
  const int*   ei    = (const int*)d_in[1];
  const int*   etyp  = (const int*)d_in[2];
  const float* ew    = (const float*)d_in[3];
  const float* rel_w = (const float*)d_in[4];
  const float* lin_w = (const float*)d_in[5];
  const float* lin_b = (const float*)d_in[6];
  const float* ln_g  = (const float*)d_in[7];
  const float* lnb   = (const float*)d_in[8];
  const float* qw    = (const float*)d_in[9];
  const int*   srcq  = (const int*)d_in[10];
  const int*   relq  = (const int*)d_in[11];
  const int*   dstq  = (const int*)d_in[12];
  float* out = (float*)d_out;

  char* ws = (char*)d_ws;
  size_t off = 0;
  auto alloc = [&](size_t bytes) -> void* {
    void* p = ws + off; off = (off + bytes + 255) & ~(size_t)255; return p;
  };
  int*    deg       = (int*)alloc((size_t)NNODES * 4);
  int*    row_start = (int*)alloc((size_t)(NNODES + 1) * 4);
  int*    cursor    = (int*)alloc((size_t)NNODES * 4);
  int*    bsum      = (int*)alloc((size_t)(NBLK + 1) * 4);
  int*    bofs      = (int*)alloc((size_t)(NBLK + 1) * 4);
  int*    s_srt     = (int*)alloc((size_t)NEDGES * 4);
  int*    t_srt     = (int*)alloc((size_t)NEDGES * 4);
  float*  w_srt     = (float*)alloc((size_t)NEDGES * 4);
  float*  scales    = (float*)alloc((size_t)NNODES * 3 * 4);
  float*  logsum    = (float*)alloc(256);
  ushort* stats_hi  = (ushort*)alloc((size_t)NNODES * 512 * 2);
  float*  xbuf      = (float*)alloc((size_t)NNODES * DIM * 4);
  ushort* xhi       = (ushort*)alloc((size_t)NNODES * DIM * 2);
  ushort* xlo       = (ushort*)alloc((size_t)NNODES * DIM * 2);
  float*  Ybuf      = (float*)alloc((size_t)NNODES * DIM * 4);
  ushort* wtbuf     = (ushort*)alloc((size_t)NLAYERS * 2 * 52 * TILE_US * 2);

  hipMemsetAsync(deg, 0, (size_t)NNODES * 4, stream);
  hipMemsetAsync(logsum, 0, 4, stream);
  deg_hist_k<<<(NEDGES + 255) / 256, 256, 0, stream>>>(ei, deg);
  logsum_k<<<(NNODES + 255) / 256, 256, 0, stream>>>(deg, logsum);
  blocksum_k<<<NBLK, 256, 0, stream>>>(deg, bsum);
  bscan_k<<<1, 256, 0, stream>>>(bsum, bofs);
  csr_offsets_k<<<NBLK, 256, 0, stream>>>(deg, bofs, row_start, cursor);
  scales_k<<<(NNODES + 255) / 256, 256, 0, stream>>>(deg, logsum, scales);
  scatter_k<<<(NEDGES + 255) / 256, 256, 0, stream>>>(ei, etyp, ew, cursor, s_srt, t_srt, w_srt);
  wsplit_k<<<(NLAYERS * KDIM * DIM + 255) / 256, 256, 0, stream>>>(lin_w, wtbuf);
  hipMemcpyAsync(xbuf, x0, (size_t)NNODES * DIM * 4, hipMemcpyDeviceToDevice, stream);
  xsplit_k<<<(NNODES * 64 + 255) / 256, 256, 0, stream>>>(x0, xhi, xlo);

  for (int l = 0; l < NLAYERS; ++l) {
    aggregate_k<<<(NNODES + 3) / 4, 256, 0, stream>>>(
        xbuf, x0, rel_w + (size_t)l * NREL * DIM, row_start, s_srt, t_srt, w_srt,
        stats_hi);
    dim3 gg((NNODES + 127) / 128, 2);
    gemm_mfma_k<<<gg, 512, 0, stream>>>(
        stats_hi, xhi, xlo, scales,
        wtbuf + (size_t)l * 2 * 52 * TILE_US, Ybuf);
    ln_k<<<(NNODES + 3) / 4, 256, 0, stream>>>(
        Ybuf, lin_b + (size_t)l * DIM, ln_g + (size_t)l * DIM, lnb + (size_t)l * DIM,
        xbuf, xhi, xlo);
  }
  score_k<<<(NTRIPLES + 3) / 4, 256, 0, stream>>>(xbuf, qw, srcq, relq, dstq, out);
}

// Round 15
// 569.371 us; speedup vs baseline: 3.8880x; 1.0547x over previous
//
#include <hip/hip_runtime.h>
#include <math.h>

#define NNODES 50000
#define NEDGES 500000
#define DIM 128
#define NREL 51
#define NLAYERS 4
#define NTRIPLES (1024*32)
#define KDIM 1664     // 13*128
#define TILE_US 4096  // one B tile = 2 planes * 64 rows * 32 ushorts (swizzled 64B rows)
#define NBLK 196      // ceil(NNODES/256)

typedef float f2 __attribute__((ext_vector_type(2)));
typedef float f32x4 __attribute__((ext_vector_type(4)));
typedef short bf16x8 __attribute__((ext_vector_type(8)));

static __device__ __forceinline__ ushort bf16_rne(float v) {
  unsigned u = __float_as_uint(v);
  unsigned r = (u + 0x7fffu + ((u >> 16) & 1u)) >> 16;
  return (ushort)r;
}
static __device__ __forceinline__ float bf16_f(ushort h) {
  return __uint_as_float(((unsigned)h) << 16);
}
static __device__ __forceinline__ f2 unpack_bf2(uint u) {
  f2 r;
  r.x = __uint_as_float(u << 16);
  r.y = __uint_as_float(u & 0xffff0000u);
  return r;
}
static __device__ __forceinline__ f2 fmax2(f2 a, f2 b) { f2 r; r.x = fmaxf(a.x,b.x); r.y = fmaxf(a.y,b.y); return r; }
static __device__ __forceinline__ f2 fmin2(f2 a, f2 b) { f2 r; r.x = fminf(a.x,b.x); r.y = fminf(a.y,b.y); return r; }

// async global->LDS, 16B per lane; LDS dest = wave-uniform base + lane*16 (linear layout only)
static __device__ __forceinline__ void gload_lds16(const void* g, void* l) {
  __builtin_amdgcn_global_load_lds(
      (const __attribute__((address_space(1))) unsigned int*)g,
      (__attribute__((address_space(3))) unsigned int*)l,
      16, 0, 0);
}

// ---------------- graph prep ----------------

__global__ void deg_hist_k(const int* __restrict__ ei, int* __restrict__ deg) {
  int e = blockIdx.x * blockDim.x + threadIdx.x;
  if (e < NEDGES) atomicAdd(&deg[ei[NEDGES + e]], 1);
}

__global__ void logsum_k(const int* __restrict__ deg, float* __restrict__ acc) {
  int i = blockIdx.x * blockDim.x + threadIdx.x;
  float v = (i < NNODES) ? logf((float)(deg[i] + 1)) : 0.0f;
  #pragma unroll
  for (int m = 32; m >= 1; m >>= 1) v += __shfl_xor(v, m, 64);
  __shared__ float ws[4];
  int lane = threadIdx.x & 63, w = threadIdx.x >> 6;
  if (lane == 0) ws[w] = v;
  __syncthreads();
  if (threadIdx.x == 0) atomicAdd(acc, ws[0] + ws[1] + ws[2] + ws[3]);
}

// ---- hierarchical scan: blocksum -> bscan -> csr_offsets ----

__global__ __launch_bounds__(256) void blocksum_k(const int* __restrict__ deg,
                                                  int* __restrict__ bsum) {
  int idx = blockIdx.x * 256 + threadIdx.x;
  int v = (idx < NNODES) ? deg[idx] : 0;
  #pragma unroll
  for (int m = 32; m >= 1; m >>= 1) v += __shfl_xor(v, m, 64);
  __shared__ int ws[4];
  int lane = threadIdx.x & 63, w = threadIdx.x >> 6;
  if (lane == 0) ws[w] = v;
  __syncthreads();
  if (threadIdx.x == 0) bsum[blockIdx.x] = ws[0] + ws[1] + ws[2] + ws[3];
}

__global__ __launch_bounds__(256) void bscan_k(const int* __restrict__ bsum,
                                               int* __restrict__ bofs) {
  int t = threadIdx.x;
  int v = (t < NBLK) ? bsum[t] : 0;
  int lane = t & 63, w = t >> 6;
  int sc = v;
  #pragma unroll
  for (int off = 1; off < 64; off <<= 1) {
    int u = __shfl_up(sc, off, 64);
    if (lane >= off) sc += u;
  }
  __shared__ int ws[4];
  if (lane == 63) ws[w] = sc;
  __syncthreads();
  int wo = 0;
  for (int i = 0; i < w; ++i) wo += ws[i];
  if (t < NBLK) bofs[t] = wo + sc - v;
}

__global__ __launch_bounds__(256) void csr_offsets_k(const int* __restrict__ deg,
                                                     const int* __restrict__ bofs,
                                                     int* __restrict__ row_start,
                                                     int* __restrict__ cursor) {
  int t = threadIdx.x;
  int idx = blockIdx.x * 256 + t;
  int v = (idx < NNODES) ? deg[idx] : 0;
  int lane = t & 63, w = t >> 6;
  int sc = v;
  #pragma unroll
  for (int off = 1; off < 64; off <<= 1) {
    int u = __shfl_up(sc, off, 64);
    if (lane >= off) sc += u;
  }
  __shared__ int ws[4];
  if (lane == 63) ws[w] = sc;
  __syncthreads();
  int wo = 0;
  for (int i = 0; i < w; ++i) wo += ws[i];
  int excl = bofs[blockIdx.x] + wo + sc - v;
  if (idx < NNODES) {
    row_start[idx] = excl;
    cursor[idx] = excl;
    if (idx == NNODES - 1) row_start[NNODES] = excl + v;
  }
}

__global__ void scales_k(const int* __restrict__ deg, const float* __restrict__ logsum,
                         float* __restrict__ scales) {
  int i = blockIdx.x * blockDim.x + threadIdx.x;
  if (i >= NNODES) return;
  float mean = *logsum / (float)NNODES;
  float sc = logf((float)(deg[i] + 1)) / mean;
  scales[i*3 + 0] = 1.0f;
  scales[i*3 + 1] = sc;
  scales[i*3 + 2] = 1.0f / fmaxf(sc, 0.01f);
}

__global__ void scatter_k(const int* __restrict__ ei, const int* __restrict__ etype,
                          const float* __restrict__ ew, int* __restrict__ cursor,
                          int* __restrict__ s_srt, int* __restrict__ t_srt,
                          float* __restrict__ w_srt) {
  int e = blockIdx.x * blockDim.x + threadIdx.x;
  if (e >= NEDGES) return;
  int d = ei[NEDGES + e];
  int pos = atomicAdd(&cursor[d], 1);
  s_srt[pos] = ei[e];
  t_srt[pos] = etype[e];
  w_srt[pos] = ew[e];
}

// ---------------- W pre-split into GEMM-ready swizzled tiles (R7 layout) ----------------

__global__ void wsplit_k(const float* __restrict__ W, ushort* __restrict__ wt) {
  int id = blockIdx.x * blockDim.x + threadIdx.x;
  if (id >= NLAYERS * KDIM * DIM) return;
  int col = id & 127;
  int k = (id >> 7) % KDIM;
  int l = id / (KDIM * DIM);
  float v = W[(size_t)l * KDIM * DIM + (size_t)k * DIM + col];
  ushort h = bf16_rne(v);
  ushort lo = bf16_rne(v - bf16_f(h));
  int c = k >> 5, kk = k & 31;
  int by = col >> 6, ch = col & 63;
  int tidx = (c < 48) ? ((c & 15) * 3 + (c >> 4)) : c;
  size_t base = (size_t)(((size_t)l * 2 + by) * 52 + tidx) * TILE_US;
  int slot = (kk >> 3) ^ ((ch >> 1) & 3);
  int off = ch * 32 + (slot << 3) + (kk & 7);
  wt[base + off] = h;
  wt[base + 2048 + off] = lo;
}

// ---------------- x -> bf16 hi/lo planes ----------------

__global__ void xsplit_k(const float* __restrict__ x, ushort* __restrict__ xh,
                         ushort* __restrict__ xl) {
  int id = blockIdx.x * blockDim.x + threadIdx.x;
  if (id >= NNODES * 64) return;
  f2 v = *(const f2*)(x + (size_t)id * 2);
  ushort h0 = bf16_rne(v.x), h1 = bf16_rne(v.y);
  ushort l0 = bf16_rne(v.x - bf16_f(h0)), l1 = bf16_rne(v.y - bf16_f(h1));
  ((uint*)xh)[id] = (uint)h0 | ((uint)h1 << 16);
  ((uint*)xl)[id] = (uint)l0 | ((uint)l1 << 16);
}

// ---------------- per-layer aggregation (one wave per destination node) ----------------
// Gathers from the bf16 HI plane of x (4B/lane/edge, halves L3 gather traffic);
// relw + self-message x0 stay fp32. Stats emitted bf16-hi only (R14).

__global__ __launch_bounds__(256) void aggregate_k(
    const ushort* __restrict__ xh, const float* __restrict__ x0,
    const float* __restrict__ relw, const int* __restrict__ row_start,
    const int* __restrict__ s_srt, const int* __restrict__ t_srt,
    const float* __restrict__ w_srt,
    ushort* __restrict__ sh)
{
  int wid = blockIdx.x * 4 + (threadIdx.x >> 6);
  if (wid >= NNODES) return;
  int lane = threadIdx.x & 63;
  int j0 = lane * 2;
  int beg = row_start[wid], end = row_start[wid + 1];
  int deg = end - beg;
  f2 sum = {0.f, 0.f}, sq = {0.f, 0.f};
  f2 mx = {-INFINITY, -INFINITY}, mn = {INFINITY, INFINITY};

  // lane-parallel preload of up to 64 edge records
  int eidx = beg + lane;
  bool va = eidx < end;
  int   sv = va ? s_srt[eidx] : 0;
  int   tv = va ? t_srt[eidx] : 0;
  float wv = va ? w_srt[eidx] : 0.0f;

  int n = (deg < 64) ? deg : 64;
  int e = 0;
  for (; e + 4 <= n; e += 4) {
    int s0 = __shfl(sv, e, 64),     s1 = __shfl(sv, e + 1, 64);
    int s2 = __shfl(sv, e + 2, 64), s3 = __shfl(sv, e + 3, 64);
    int t0 = __shfl(tv, e, 64),     t1 = __shfl(tv, e + 1, 64);
    int t2 = __shfl(tv, e + 2, 64), t3 = __shfl(tv, e + 3, 64);
    float w0 = __shfl(wv, e, 64),     w1 = __shfl(wv, e + 1, 64);
    float w2 = __shfl(wv, e + 2, 64), w3 = __shfl(wv, e + 3, 64);
    f2 xa = unpack_bf2(*(const uint*)(xh + (size_t)s0 * DIM + j0));
    f2 xb = unpack_bf2(*(const uint*)(xh + (size_t)s1 * DIM + j0));
    f2 xc = unpack_bf2(*(const uint*)(xh + (size_t)s2 * DIM + j0));
    f2 xd = unpack_bf2(*(const uint*)(xh + (size_t)s3 * DIM + j0));
    f2 ra = *(const f2*)(relw + (size_t)t0 * DIM + j0);
    f2 rb = *(const f2*)(relw + (size_t)t1 * DIM + j0);
    f2 rc = *(const f2*)(relw + (size_t)t2 * DIM + j0);
    f2 rd = *(const f2*)(relw + (size_t)t3 * DIM + j0);
    f2 m0 = xa * ra * w0;
    f2 m1 = xb * rb * w1;
    f2 m2 = xc * rc * w2;
    f2 m3 = xd * rd * w3;
    sum += m0 + m1 + m2 + m3;
    sq += m0*m0 + m1*m1 + m2*m2 + m3*m3;
    mx = fmax2(fmax2(fmax2(mx, m0), fmax2(m1, m2)), m3);
    mn = fmin2(fmin2(fmin2(mn, m0), fmin2(m1, m2)), m3);
  }
  for (; e < n; ++e) {
    int s = __shfl(sv, e, 64);
    int ty = __shfl(tv, e, 64);
    float w = __shfl(wv, e, 64);
    f2 xs = unpack_bf2(*(const uint*)(xh + (size_t)s * DIM + j0));
    f2 rv = *(const f2*)(relw + (size_t)ty * DIM + j0);
    f2 m = xs * rv * w;
    sum += m; sq += m * m;
    mx = fmax2(mx, m); mn = fmin2(mn, m);
  }
  // rare overflow path (deg > 64)
  for (int ee = beg + 64; ee < end; ++ee) {
    int s = s_srt[ee]; int ty = t_srt[ee]; float w = w_srt[ee];
    f2 xs = unpack_bf2(*(const uint*)(xh + (size_t)s * DIM + j0));
    f2 rv = *(const f2*)(relw + (size_t)ty * DIM + j0);
    f2 m = xs * rv * w;
    sum += m; sq += m * m;
    mx = fmax2(mx, m); mn = fmin2(mn, m);
  }

  f2 x0v = *(const f2*)(x0 + (size_t)wid * DIM + j0);
  sum += x0v; sq += x0v * x0v;
  mx = fmax2(mx, x0v); mn = fmin2(mn, x0v);
  float dq = (float)(deg + 1);
  f2 mean = sum / dq;
  f2 sqm = sq / dq;
  f2 var = sqm - mean * mean;
  f2 sd; sd.x = sqrtf(fmaxf(var.x, 1e-6f)); sd.y = sqrtf(fmaxf(var.y, 1e-6f));
  f2 feats[4] = {mean, mx, mn, sd};
  size_t base = (size_t)wid * 512 + j0;
  #pragma unroll
  for (int f = 0; f < 4; ++f) {
    f2 v = feats[f];
    ushort h0 = bf16_rne(v.x), h1 = bf16_rne(v.y);
    *(uint*)(sh + base + f * 128) = (uint)h0 | ((uint)h1 << 16);
  }
}

// ---------------- scale-folded split-bf16 MFMA GEMM (R14 version) ----------------
// Stat chunks (cp<16): A = bf16-hi only -> 2-term MFMA. x chunks (cp>=16): 3-term.

__global__ __launch_bounds__(512, 2) void gemm_mfma_k(
    const ushort* __restrict__ sh,
    const ushort* __restrict__ xh, const ushort* __restrict__ xl,
    const float* __restrict__ scales, const ushort* __restrict__ wtl,
    float* __restrict__ Y)
{
  __shared__ ushort As[2 * TILE_US];      // hi [128][32]; lo [128][32] (x chunks only)
  __shared__ ushort Bs[2][3 * TILE_US];   // double-buffered, up to 3 s-tiles
  int t = threadIdx.x;
  int w = t >> 6, lane = t & 63;
  int lr = lane & 15, lk = lane >> 4;
  int wr = w >> 1, wcq = w & 1;
  int row0 = blockIdx.x * 128;
  int by = blockIdx.y;

  // staging role: A row sr (0..127), slot sq
  int sr = t >> 2, sq = t & 3;
  int an = row0 + sr; if (an >= NNODES) an = NNODES - 1;
  int aoff = sr * 32 + ((sq ^ ((sr >> 1) & 3)) << 3);

  f32x4 p0_00, p0_01, p0_10, p0_11;
  f32x4 p1_00, p1_01, p1_10, p1_11;
  f32x4 p2_00, p2_01, p2_10, p2_11;
  p0_00 = p0_01 = p0_10 = p0_11 = (f32x4){0.f,0.f,0.f,0.f};
  p1_00 = p1_01 = p1_10 = p1_11 = (f32x4){0.f,0.f,0.f,0.f};
  p2_00 = p2_01 = p2_10 = p2_11 = (f32x4){0.f,0.f,0.f,0.f};

  bf16x8 rh, rl;
  auto loadA = [&](int cp) {
    if (cp < 16) {
      rh = *(const bf16x8*)(sh + (size_t)an * 512 + cp * 32 + sq * 8);
    } else {
      rh = *(const bf16x8*)(xh + (size_t)an * 128 + (cp - 16) * 32 + sq * 8);
      rl = *(const bf16x8*)(xl + (size_t)an * 128 + (cp - 16) * 32 + sq * 8);
    }
  };
  auto issueB = [&](int cp, ushort* dst) {
    int tile0 = (cp < 16) ? cp * 3 : cp + 32;
    const char* src = (const char*)(wtl + ((size_t)by * 52 + tile0) * TILE_US);
    char* d = (char*)dst;
    gload_lds16(src + t * 16, d + t * 16);
    if (cp < 16) {
      gload_lds16(src + (512 + t) * 16, d + (512 + t) * 16);
      gload_lds16(src + (1024 + t) * 16, d + (1024 + t) * 16);
    }
  };

  // prologue: stage chunk 0
  issueB(0, Bs[0]);
  loadA(0);
  *(bf16x8*)(As + aoff) = rh;
  __syncthreads();   // drains B(0) vmcnt + publishes As(0)

  int cur = 0;
  const int ar = wr * 32 + lr;
  const int aswz = ar * 32 + ((lk ^ ((ar >> 1) & 3)) << 3);
  const int br = wcq * 32 + lr;
  const int bswz = br * 32 + ((lk ^ ((br >> 1) & 3)) << 3);

#define LOADB(Btile)                                                               \
    const ushort* Bb = (Btile) + bswz;                                             \
    bf16x8 bh0 = *(const bf16x8*)(Bb);                                             \
    bf16x8 bl0 = *(const bf16x8*)(Bb + 2048);                                      \
    bf16x8 bh1 = *(const bf16x8*)(Bb + 512);                                       \
    bf16x8 bl1 = *(const bf16x8*)(Bb + 2048 + 512);

#define MFMA_S2(pa, pb, pc, pd, Btile)                                             \
  {                                                                                \
    LOADB(Btile)                                                                   \
    pa = __builtin_amdgcn_mfma_f32_16x16x32_bf16(ah0, bh0, pa, 0,0,0);             \
    pa = __builtin_amdgcn_mfma_f32_16x16x32_bf16(ah0, bl0, pa, 0,0,0);             \
    pb = __builtin_amdgcn_mfma_f32_16x16x32_bf16(ah0, bh1, pb, 0,0,0);             \
    pb = __builtin_amdgcn_mfma_f32_16x16x32_bf16(ah0, bl1, pb, 0,0,0);             \
    pc = __builtin_amdgcn_mfma_f32_16x16x32_bf16(ah1, bh0, pc, 0,0,0);             \
    pc = __builtin_amdgcn_mfma_f32_16x16x32_bf16(ah1, bl0, pc, 0,0,0);             \
    pd = __builtin_amdgcn_mfma_f32_16x16x32_bf16(ah1, bh1, pd, 0,0,0);             \
    pd = __builtin_amdgcn_mfma_f32_16x16x32_bf16(ah1, bl1, pd, 0,0,0);             \
  }

#define MFMA_S3(pa, pb, pc, pd, Btile)                                             \
  {                                                                                \
    LOADB(Btile)                                                                   \
    pa = __builtin_amdgcn_mfma_f32_16x16x32_bf16(ah0, bh0, pa, 0,0,0);             \
    pa = __builtin_amdgcn_mfma_f32_16x16x32_bf16(ah0, bl0, pa, 0,0,0);             \
    pa = __builtin_amdgcn_mfma_f32_16x16x32_bf16(al0, bh0, pa, 0,0,0);             \
    pb = __builtin_amdgcn_mfma_f32_16x16x32_bf16(ah0, bh1, pb, 0,0,0);             \
    pb = __builtin_amdgcn_mfma_f32_16x16x32_bf16(ah0, bl1, pb, 0,0,0);             \
    pb = __builtin_amdgcn_mfma_f32_16x16x32_bf16(al0, bh1, pb, 0,0,0);             \
    pc = __builtin_amdgcn_mfma_f32_16x16x32_bf16(ah1, bh0, pc, 0,0,0);             \
    pc = __builtin_amdgcn_mfma_f32_16x16x32_bf16(ah1, bl0, pc, 0,0,0);             \
    pc = __builtin_amdgcn_mfma_f32_16x16x32_bf16(al1, bh0, pc, 0,0,0);             \
    pd = __builtin_amdgcn_mfma_f32_16x16x32_bf16(ah1, bh1, pd, 0,0,0);             \
    pd = __builtin_amdgcn_mfma_f32_16x16x32_bf16(ah1, bl1, pd, 0,0,0);             \
    pd = __builtin_amdgcn_mfma_f32_16x16x32_bf16(al1, bh1, pd, 0,0,0);             \
  }

  for (int cp = 0; cp < 20; ++cp) {
    // issue next chunk's loads FIRST (overlap with compute below)
    if (cp < 19) {
      issueB(cp + 1, Bs[cur ^ 1]);
      loadA(cp + 1);
    }
    // ---- compute from As, Bs[cur] ----
    const ushort* Ab = As + aswz;
    const ushort* Bcur = Bs[cur];
    if (cp < 16) {
      bf16x8 ah0 = *(const bf16x8*)(Ab);
      bf16x8 ah1 = *(const bf16x8*)(Ab + 512);
      MFMA_S2(p0_00, p0_01, p0_10, p0_11, Bcur);
      MFMA_S2(p1_00, p1_01, p1_10, p1_11, Bcur + TILE_US);
      MFMA_S2(p2_00, p2_01, p2_10, p2_11, Bcur + 2 * TILE_US);
    } else {
      bf16x8 ah0 = *(const bf16x8*)(Ab);
      bf16x8 al0 = *(const bf16x8*)(Ab + TILE_US);
      bf16x8 ah1 = *(const bf16x8*)(Ab + 512);
      bf16x8 al1 = *(const bf16x8*)(Ab + TILE_US + 512);
      MFMA_S3(p0_00, p0_01, p0_10, p0_11, Bcur);
    }
    __syncthreads();   // drains B(cp+1) (landed during compute); As/Bs reads done
    if (cp < 19) {
      *(bf16x8*)(As + aoff) = rh;                           // A(cp+1) hi -> LDS
      if (cp + 1 >= 16) *(bf16x8*)(As + TILE_US + aoff) = rl;  // lo only for x chunks
    }
    cur ^= 1;
    __syncthreads();   // publish As(cp+1); vmcnt already drained -> cheap
  }
#undef MFMA_S2
#undef MFMA_S3
#undef LOADB

  // ---- epilogue: fold scales, write Y ----
  int colg = by * 64 + wcq * 32;
  f32x4 q0[2][2] = {{p0_00, p0_01}, {p0_10, p0_11}};
  f32x4 q1[2][2] = {{p1_00, p1_01}, {p1_10, p1_11}};
  f32x4 q2[2][2] = {{p2_00, p2_01}, {p2_10, p2_11}};
  #pragma unroll
  for (int fr = 0; fr < 2; ++fr) {
    int rbase = row0 + wr * 32 + fr * 16 + lk * 4;
    #pragma unroll
    for (int q = 0; q < 4; ++q) {
      int r = rbase + q;
      int rc = (r < NNODES) ? r : (NNODES - 1);
      float s1 = scales[rc * 3 + 1];
      float s2 = scales[rc * 3 + 2];
      if (r < NNODES) {
        #pragma unroll
        for (int fc = 0; fc < 2; ++fc) {
          float o = q0[fr][fc][q] + s1 * q1[fr][fc][q] + s2 * q2[fr][fc][q];
          Y[(size_t)r * DIM + colg + fc * 16 + lr] = o;
        }
      }
    }
  }
}

// ---------------- bias + LN + relu + residual; also emit x hi/lo planes ----------------

__global__ __launch_bounds__(256) void ln_k(
    const float* __restrict__ Y, const float* __restrict__ bias,
    const float* __restrict__ gam, const float* __restrict__ bet,
    float* __restrict__ x, ushort* __restrict__ xh, ushort* __restrict__ xl)
{
  int wid = blockIdx.x * 4 + (threadIdx.x >> 6);
  if (wid >= NNODES) return;
  int lane = threadIdx.x & 63;
  int j0 = lane * 2;
  f2 v = *(const f2*)(Y + (size_t)wid * DIM + j0);
  f2 b = *(const f2*)(bias + j0);
  v += b;
  float s = v.x + v.y;
  float q = v.x * v.x + v.y * v.y;
  #pragma unroll
  for (int m = 1; m < 64; m <<= 1) { s += __shfl_xor(s, m, 64); q += __shfl_xor(q, m, 64); }
  float mu = s * (1.0f / 128.0f);
  float var = q * (1.0f / 128.0f) - mu * mu;
  float rstd = rsqrtf(var + 1e-5f);
  f2 g = *(const f2*)(gam + j0);
  f2 be = *(const f2*)(bet + j0);
  f2 o = (v - mu) * rstd * g + be;
  o.x = fmaxf(o.x, 0.f); o.y = fmaxf(o.y, 0.f);
  float* xp = x + (size_t)wid * DIM + j0;
  f2 xr = *(const f2*)xp;
  f2 res = o + xr;
  *(f2*)xp = res;
  ushort h0 = bf16_rne(res.x), h1 = bf16_rne(res.y);
  ushort l0 = bf16_rne(res.x - bf16_f(h0)), l1 = bf16_rne(res.y - bf16_f(h1));
  *(uint*)(xh + (size_t)wid * 128 + j0) = (uint)h0 | ((uint)h1 << 16);
  *(uint*)(xl + (size_t)wid * 128 + j0) = (uint)l0 | ((uint)l1 << 16);
}

// ---------------- distmult scoring ----------------

__global__ __launch_bounds__(256) void score_k(
    const float* __restrict__ x, const float* __restrict__ qw,
    const int* __restrict__ src, const int* __restrict__ rel,
    const int* __restrict__ dst, float* __restrict__ out)
{
  int wid = blockIdx.x * 4 + (threadIdx.x >> 6);
  if (wid >= NTRIPLES) return;
  int lane = threadIdx.x & 63;
  int j0 = lane * 2;
  int s = src[wid], r = rel[wid], d = dst[wid];
  f2 xs = *(const f2*)(x  + (size_t)s * DIM + j0);
  f2 q  = *(const f2*)(qw + (size_t)r * DIM + j0);
  f2 xd = *(const f2*)(x  + (size_t)d * DIM + j0);
  float p = xs.x*q.x*xd.x + xs.y*q.y*xd.y;
  #pragma unroll
  for (int m = 32; m >= 1; m >>= 1) p += __shfl_xor(p, m, 64);
  if (lane == 0) out[wid] = p;
}

// ---------------- launch ----------------

extern "C" void kernel_launch(void* const* d_in, const int* in_sizes, int n_in,
                              void* d_out, int out_size, void* d_ws, size_t ws_size,
                              hipStream_t stream) {
  const float* x0    = (const float*)d_in[0];
  const int*   ei    = (const int*)d_in[1];
  const int*   etyp  = (const int*)d_in[2];
  const float* ew    = (const float*)d_in[3];
  const float* rel_w = (const float*)d_in[4];
  const float* lin_w = (const float*)d_in[5];
  const float* lin_b = (const float*)d_in[6];
  const float* ln_g  = (const float*)d_in[7];
  const float* lnb   = (const float*)d_in[8];
  const float* qw    = (const float*)d_in[9];
  const int*   srcq  = (const int*)d_in[10];
  const int*   relq  = (const int*)d_in[11];
  const int*   dstq  = (const int*)d_in[12];
  float* out = (float*)d_out;

  char* ws = (char*)d_ws;
  size_t off = 0;
  auto alloc = [&](size_t bytes) -> void* {
    void* p = ws + off; off = (off + bytes + 255) & ~(size_t)255; return p;
  };
  int*    deg       = (int*)alloc((size_t)NNODES * 4);
  int*    row_start = (int*)alloc((size_t)(NNODES + 1) * 4);
  int*    cursor    = (int*)alloc((size_t)NNODES * 4);
  int*    bsum      = (int*)alloc((size_t)(NBLK + 1) * 4);
  int*    bofs      = (int*)alloc((size_t)(NBLK + 1) * 4);
  int*    s_srt     = (int*)alloc((size_t)NEDGES * 4);
  int*    t_srt     = (int*)alloc((size_t)NEDGES * 4);
  float*  w_srt     = (float*)alloc((size_t)NEDGES * 4);
  float*  scales    = (float*)alloc((size_t)NNODES * 3 * 4);
  float*  logsum    = (float*)alloc(256);
  ushort* stats_hi  = (ushort*)alloc((size_t)NNODES * 512 * 2);
  float*  xbuf      = (float*)alloc((size_t)NNODES * DIM * 4);
  ushort* xhi       = (ushort*)alloc((size_t)NNODES * DIM * 2);
  ushort* xlo       = (ushort*)alloc((size_t)NNODES * DIM * 2);
  float*  Ybuf      = (float*)alloc((size_t)NNODES * DIM * 4);
  ushort* wtbuf     = (ushort*)alloc((size_t)NLAYERS * 2 * 52 * TILE_US * 2);

  hipMemsetAsync(deg, 0, (size_t)NNODES * 4, stream);
  hipMemsetAsync(logsum, 0, 4, stream);
  deg_hist_k<<<(NEDGES + 255) / 256, 256, 0, stream>>>(ei, deg);
  logsum_k<<<(NNODES + 255) / 256, 256, 0, stream>>>(deg, logsum);
  blocksum_k<<<NBLK, 256, 0, stream>>>(deg, bsum);
  bscan_k<<<1, 256, 0, stream>>>(bsum, bofs);
  csr_offsets_k<<<NBLK, 256, 0, stream>>>(deg, bofs, row_start, cursor);
  scales_k<<<(NNODES + 255) / 256, 256, 0, stream>>>(deg, logsum, scales);
  scatter_k<<<(NEDGES + 255) / 256, 256, 0, stream>>>(ei, etyp, ew, cursor, s_srt, t_srt, w_srt);
  wsplit_k<<<(NLAYERS * KDIM * DIM + 255) / 256, 256, 0, stream>>>(lin_w, wtbuf);
  hipMemcpyAsync(xbuf, x0, (size_t)NNODES * DIM * 4, hipMemcpyDeviceToDevice, stream);
  xsplit_k<<<(NNODES * 64 + 255) / 256, 256, 0, stream>>>(x0, xhi, xlo);

  for (int l = 0; l < NLAYERS; ++l) {
    aggregate_k<<<(NNODES + 3) / 4, 256, 0, stream>>>(
        xhi, x0, rel_w + (size_t)l * NREL * DIM, row_start, s_srt, t_srt, w_srt,
        stats_hi);
    dim3 gg((NNODES + 127) / 128, 2);
    gemm_mfma_k<<<gg, 512, 0, stream>>>(
        stats_hi, xhi, xlo, scales,
        wtbuf + (size_t)l * 2 * 52 * TILE_US, Ybuf);
    ln_k<<<(NNODES + 3) / 4, 256, 0, stream>>>(
        Ybuf, lin_b + (size_t)l * DIM, ln_g + (size_t)l * DIM, lnb + (size_t)l * DIM,
        xbuf, xhi, xlo);
  }
  score_k<<<(NTRIPLES + 3) / 4, 256, 0, stream>>>(xbuf, qw, srcq, relq, dstq, out);
}

// Round 16
// 550.098 us; speedup vs baseline: 4.0242x; 1.0350x over previous
//
#include <hip/hip_runtime.h>
#include <math.h>

#define NNODES 50000
#define NEDGES 500000
#define DIM 128
#define NREL 51
#define NLAYERS 4
#define NTRIPLES (1024*32)
#define KDIM 1664     // 13*128
#define TILE_US 8192  // one B s-tile = 2 planes * 128 cols * 32 us (swizzled 64B rows)
#define NBLK 196      // ceil(NNODES/256)

typedef float f2 __attribute__((ext_vector_type(2)));
typedef float f32x4 __attribute__((ext_vector_type(4)));
typedef short bf16x8 __attribute__((ext_vector_type(8)));

static __device__ __forceinline__ ushort bf16_rne(float v) {
  unsigned u = __float_as_uint(v);
  unsigned r = (u + 0x7fffu + ((u >> 16) & 1u)) >> 16;
  return (ushort)r;
}
static __device__ __forceinline__ float bf16_f(ushort h) {
  return __uint_as_float(((unsigned)h) << 16);
}
static __device__ __forceinline__ f2 unpack_bf2(uint u) {
  f2 r;
  r.x = __uint_as_float(u << 16);
  r.y = __uint_as_float(u & 0xffff0000u);
  return r;
}
static __device__ __forceinline__ f2 fmax2(f2 a, f2 b) { f2 r; r.x = fmaxf(a.x,b.x); r.y = fmaxf(a.y,b.y); return r; }
static __device__ __forceinline__ f2 fmin2(f2 a, f2 b) { f2 r; r.x = fminf(a.x,b.x); r.y = fminf(a.y,b.y); return r; }

// async global->LDS, 16B per lane; LDS dest = wave-uniform base + lane*16 (linear layout only)
static __device__ __forceinline__ void gload_lds16(const void* g, void* l) {
  __builtin_amdgcn_global_load_lds(
      (const __attribute__((address_space(1))) unsigned int*)g,
      (__attribute__((address_space(3))) unsigned int*)l,
      16, 0, 0);
}

// ---------------- graph prep ----------------

__global__ void deg_hist_k(const int* __restrict__ ei, int* __restrict__ deg) {
  int e = blockIdx.x * blockDim.x + threadIdx.x;
  if (e < NEDGES) atomicAdd(&deg[ei[NEDGES + e]], 1);
}

__global__ void logsum_k(const int* __restrict__ deg, float* __restrict__ acc) {
  int i = blockIdx.x * blockDim.x + threadIdx.x;
  float v = (i < NNODES) ? logf((float)(deg[i] + 1)) : 0.0f;
  #pragma unroll
  for (int m = 32; m >= 1; m >>= 1) v += __shfl_xor(v, m, 64);
  __shared__ float ws[4];
  int lane = threadIdx.x & 63, w = threadIdx.x >> 6;
  if (lane == 0) ws[w] = v;
  __syncthreads();
  if (threadIdx.x == 0) atomicAdd(acc, ws[0] + ws[1] + ws[2] + ws[3]);
}

// ---- hierarchical scan: blocksum -> bscan -> csr_offsets ----

__global__ __launch_bounds__(256) void blocksum_k(const int* __restrict__ deg,
                                                  int* __restrict__ bsum) {
  int idx = blockIdx.x * 256 + threadIdx.x;
  int v = (idx < NNODES) ? deg[idx] : 0;
  #pragma unroll
  for (int m = 32; m >= 1; m >>= 1) v += __shfl_xor(v, m, 64);
  __shared__ int ws[4];
  int lane = threadIdx.x & 63, w = threadIdx.x >> 6;
  if (lane == 0) ws[w] = v;
  __syncthreads();
  if (threadIdx.x == 0) bsum[blockIdx.x] = ws[0] + ws[1] + ws[2] + ws[3];
}

__global__ __launch_bounds__(256) void bscan_k(const int* __restrict__ bsum,
                                               int* __restrict__ bofs) {
  int t = threadIdx.x;
  int v = (t < NBLK) ? bsum[t] : 0;
  int lane = t & 63, w = t >> 6;
  int sc = v;
  #pragma unroll
  for (int off = 1; off < 64; off <<= 1) {
    int u = __shfl_up(sc, off, 64);
    if (lane >= off) sc += u;
  }
  __shared__ int ws[4];
  if (lane == 63) ws[w] = sc;
  __syncthreads();
  int wo = 0;
  for (int i = 0; i < w; ++i) wo += ws[i];
  if (t < NBLK) bofs[t] = wo + sc - v;
}

__global__ __launch_bounds__(256) void csr_offsets_k(const int* __restrict__ deg,
                                                     const int* __restrict__ bofs,
                                                     int* __restrict__ row_start,
                                                     int* __restrict__ cursor) {
  int t = threadIdx.x;
  int idx = blockIdx.x * 256 + t;
  int v = (idx < NNODES) ? deg[idx] : 0;
  int lane = t & 63, w = t >> 6;
  int sc = v;
  #pragma unroll
  for (int off = 1; off < 64; off <<= 1) {
    int u = __shfl_up(sc, off, 64);
    if (lane >= off) sc += u;
  }
  __shared__ int ws[4];
  if (lane == 63) ws[w] = sc;
  __syncthreads();
  int wo = 0;
  for (int i = 0; i < w; ++i) wo += ws[i];
  int excl = bofs[blockIdx.x] + wo + sc - v;
  if (idx < NNODES) {
    row_start[idx] = excl;
    cursor[idx] = excl;
    if (idx == NNODES - 1) row_start[NNODES] = excl + v;
  }
}

__global__ void scales_k(const int* __restrict__ deg, const float* __restrict__ logsum,
                         float* __restrict__ scales) {
  int i = blockIdx.x * blockDim.x + threadIdx.x;
  if (i >= NNODES) return;
  float mean = *logsum / (float)NNODES;
  float sc = logf((float)(deg[i] + 1)) / mean;
  scales[i*3 + 0] = 1.0f;
  scales[i*3 + 1] = sc;
  scales[i*3 + 2] = 1.0f / fmaxf(sc, 0.01f);
}

__global__ void scatter_k(const int* __restrict__ ei, const int* __restrict__ etype,
                          const float* __restrict__ ew, int* __restrict__ cursor,
                          int* __restrict__ s_srt, int* __restrict__ t_srt,
                          float* __restrict__ w_srt) {
  int e = blockIdx.x * blockDim.x + threadIdx.x;
  if (e >= NEDGES) return;
  int d = ei[NEDGES + e];
  int pos = atomicAdd(&cursor[d], 1);
  s_srt[pos] = ei[e];
  t_srt[pos] = etype[e];
  w_srt[pos] = ew[e];
}

// ---------------- W pre-split into GEMM-ready swizzled tiles (128-col tiles) ----------------
// Tile = [plane hi/lo][128 cols][32 us]; swizzle: off = ch*32 + ((slot^((ch>>1)&3))<<3) + (kk&7).
// Tile order: wt[l*52 + tidx], tidx = (c<48) ? (c&15)*3 + (c>>4) : c.

__global__ void wsplit_k(const float* __restrict__ W, ushort* __restrict__ wt) {
  int id = blockIdx.x * blockDim.x + threadIdx.x;
  if (id >= NLAYERS * KDIM * DIM) return;
  int col = id & 127;
  int k = (id >> 7) % KDIM;
  int l = id / (KDIM * DIM);
  float v = W[(size_t)l * KDIM * DIM + (size_t)k * DIM + col];
  ushort h = bf16_rne(v);
  ushort lo = bf16_rne(v - bf16_f(h));
  int c = k >> 5, kk = k & 31;
  int tidx = (c < 48) ? ((c & 15) * 3 + (c >> 4)) : c;
  size_t base = (size_t)((size_t)l * 52 + tidx) * TILE_US;
  int slot = (kk >> 3) ^ ((col >> 1) & 3);
  int off = col * 32 + (slot << 3) + (kk & 7);
  wt[base + off] = h;
  wt[base + 4096 + off] = lo;
}

// ---------------- x -> bf16 hi/lo planes ----------------

__global__ void xsplit_k(const float* __restrict__ x, ushort* __restrict__ xh,
                         ushort* __restrict__ xl) {
  int id = blockIdx.x * blockDim.x + threadIdx.x;
  if (id >= NNODES * 64) return;
  f2 v = *(const f2*)(x + (size_t)id * 2);
  ushort h0 = bf16_rne(v.x), h1 = bf16_rne(v.y);
  ushort l0 = bf16_rne(v.x - bf16_f(h0)), l1 = bf16_rne(v.y - bf16_f(h1));
  ((uint*)xh)[id] = (uint)h0 | ((uint)h1 << 16);
  ((uint*)xl)[id] = (uint)l0 | ((uint)l1 << 16);
}

// ---------------- per-layer aggregation (one wave per destination node) ----------------

__global__ __launch_bounds__(256) void aggregate_k(
    const ushort* __restrict__ xh, const float* __restrict__ x0,
    const float* __restrict__ relw, const int* __restrict__ row_start,
    const int* __restrict__ s_srt, const int* __restrict__ t_srt,
    const float* __restrict__ w_srt,
    ushort* __restrict__ sh)
{
  int wid = blockIdx.x * 4 + (threadIdx.x >> 6);
  if (wid >= NNODES) return;
  int lane = threadIdx.x & 63;
  int j0 = lane * 2;
  int beg = row_start[wid], end = row_start[wid + 1];
  int deg = end - beg;
  f2 sum = {0.f, 0.f}, sq = {0.f, 0.f};
  f2 mx = {-INFINITY, -INFINITY}, mn = {INFINITY, INFINITY};

  int eidx = beg + lane;
  bool va = eidx < end;
  int   sv = va ? s_srt[eidx] : 0;
  int   tv = va ? t_srt[eidx] : 0;
  float wv = va ? w_srt[eidx] : 0.0f;

  int n = (deg < 64) ? deg : 64;
  int e = 0;
  for (; e + 4 <= n; e += 4) {
    int s0 = __shfl(sv, e, 64),     s1 = __shfl(sv, e + 1, 64);
    int s2 = __shfl(sv, e + 2, 64), s3 = __shfl(sv, e + 3, 64);
    int t0 = __shfl(tv, e, 64),     t1 = __shfl(tv, e + 1, 64);
    int t2 = __shfl(tv, e + 2, 64), t3 = __shfl(tv, e + 3, 64);
    float w0 = __shfl(wv, e, 64),     w1 = __shfl(wv, e + 1, 64);
    float w2 = __shfl(wv, e + 2, 64), w3 = __shfl(wv, e + 3, 64);
    f2 xa = unpack_bf2(*(const uint*)(xh + (size_t)s0 * DIM + j0));
    f2 xb = unpack_bf2(*(const uint*)(xh + (size_t)s1 * DIM + j0));
    f2 xc = unpack_bf2(*(const uint*)(xh + (size_t)s2 * DIM + j0));
    f2 xd = unpack_bf2(*(const uint*)(xh + (size_t)s3 * DIM + j0));
    f2 ra = *(const f2*)(relw + (size_t)t0 * DIM + j0);
    f2 rb = *(const f2*)(relw + (size_t)t1 * DIM + j0);
    f2 rc = *(const f2*)(relw + (size_t)t2 * DIM + j0);
    f2 rd = *(const f2*)(relw + (size_t)t3 * DIM + j0);
    f2 m0 = xa * ra * w0;
    f2 m1 = xb * rb * w1;
    f2 m2 = xc * rc * w2;
    f2 m3 = xd * rd * w3;
    sum += m0 + m1 + m2 + m3;
    sq += m0*m0 + m1*m1 + m2*m2 + m3*m3;
    mx = fmax2(fmax2(fmax2(mx, m0), fmax2(m1, m2)), m3);
    mn = fmin2(fmin2(fmin2(mn, m0), fmin2(m1, m2)), m3);
  }
  for (; e < n; ++e) {
    int s = __shfl(sv, e, 64);
    int ty = __shfl(tv, e, 64);
    float w = __shfl(wv, e, 64);
    f2 xs = unpack_bf2(*(const uint*)(xh + (size_t)s * DIM + j0));
    f2 rv = *(const f2*)(relw + (size_t)ty * DIM + j0);
    f2 m = xs * rv * w;
    sum += m; sq += m * m;
    mx = fmax2(mx, m); mn = fmin2(mn, m);
  }
  for (int ee = beg + 64; ee < end; ++ee) {
    int s = s_srt[ee]; int ty = t_srt[ee]; float w = w_srt[ee];
    f2 xs = unpack_bf2(*(const uint*)(xh + (size_t)s * DIM + j0));
    f2 rv = *(const f2*)(relw + (size_t)ty * DIM + j0);
    f2 m = xs * rv * w;
    sum += m; sq += m * m;
    mx = fmax2(mx, m); mn = fmin2(mn, m);
  }

  f2 x0v = *(const f2*)(x0 + (size_t)wid * DIM + j0);
  sum += x0v; sq += x0v * x0v;
  mx = fmax2(mx, x0v); mn = fmin2(mn, x0v);
  float dq = (float)(deg + 1);
  f2 mean = sum / dq;
  f2 sqm = sq / dq;
  f2 var = sqm - mean * mean;
  f2 sd; sd.x = sqrtf(fmaxf(var.x, 1e-6f)); sd.y = sqrtf(fmaxf(var.y, 1e-6f));
  f2 feats[4] = {mean, mx, mn, sd};
  size_t base = (size_t)wid * 512 + j0;
  #pragma unroll
  for (int f = 0; f < 4; ++f) {
    f2 v = feats[f];
    ushort h0 = bf16_rne(v.x), h1 = bf16_rne(v.y);
    *(uint*)(sh + base + f * 128) = (uint)h0 | ((uint)h1 << 16);
  }
}

// ---------------- fused GEMM + bias + LN + relu + residual + bf16-split ----------------
// 64-row x 128-col tile (full DIM -> LN block-local). 8 waves = 2 rg x 4 cg, wave 32x32.
// Single-buffered B (48 KB) + A (8 KB) = 56 KB -> 2 blocks/CU. Grid 782.
// Stat chunks 2-term (A hi only); x chunks 3-term. LN epilogue via LDS out-tile
// aliased onto Bs ([64][132] f32, pitch dodges bank conflicts).

__global__ __launch_bounds__(512, 2) void gemm_fused_k(
    const ushort* __restrict__ sh,
    const ushort* __restrict__ xh, const ushort* __restrict__ xl,
    const float* __restrict__ scales, const ushort* __restrict__ wtl,
    const float* __restrict__ bias, const float* __restrict__ gam,
    const float* __restrict__ bet, float* __restrict__ x,
    ushort* __restrict__ xho, ushort* __restrict__ xlo)
{
  __shared__ ushort As[2 * 2048];      // hi [64][32], lo [64][32] (swizzled rows)
  __shared__ ushort Bs[3 * TILE_US];   // 48 KB; aliased as out-tile [64][132] f32 in epilogue
  int t = threadIdx.x;
  int w = t >> 6, lane = t & 63;
  int lr = lane & 15, lk = lane >> 4;
  int rg = w >> 2, cg = w & 3;
  int row0 = blockIdx.x * 64;

  // staging role: t<256 -> hi plane, t>=256 -> lo plane; row sr, slot sq
  int th = t & 255;
  int sr = th >> 2, sq = th & 3;
  int an = row0 + sr; if (an >= NNODES) an = NNODES - 1;
  int aoff = sr * 32 + ((sq ^ ((sr >> 1) & 3)) << 3);

  f32x4 p0_00, p0_01, p0_10, p0_11;
  f32x4 p1_00, p1_01, p1_10, p1_11;
  f32x4 p2_00, p2_01, p2_10, p2_11;
  p0_00 = p0_01 = p0_10 = p0_11 = (f32x4){0.f,0.f,0.f,0.f};
  p1_00 = p1_01 = p1_10 = p1_11 = (f32x4){0.f,0.f,0.f,0.f};
  p2_00 = p2_01 = p2_10 = p2_11 = (f32x4){0.f,0.f,0.f,0.f};

  bf16x8 rr;
  auto loadA = [&](int cp) {
    if (t < 256) {
      if (cp < 16) rr = *(const bf16x8*)(sh + (size_t)an * 512 + cp * 32 + sq * 8);
      else         rr = *(const bf16x8*)(xh + (size_t)an * 128 + (cp - 16) * 32 + sq * 8);
    } else if (cp >= 16) {
      rr = *(const bf16x8*)(xl + (size_t)an * 128 + (cp - 16) * 32 + sq * 8);
    }
  };
  auto writeA = [&](int cp) {
    if (t < 256) *(bf16x8*)(As + aoff) = rr;
    else if (cp >= 16) *(bf16x8*)(As + 2048 + aoff) = rr;
  };
  auto issueB = [&](int cp) {
    int tile0 = (cp < 16) ? cp * 3 : cp + 32;
    const char* src = (const char*)(wtl + (size_t)tile0 * TILE_US);
    char* d = (char*)Bs;
    gload_lds16(src + t * 16, d + t * 16);
    gload_lds16(src + (512 + t) * 16, d + (512 + t) * 16);
    if (cp < 16) {
      gload_lds16(src + (1024 + t) * 16, d + (1024 + t) * 16);
      gload_lds16(src + (1536 + t) * 16, d + (1536 + t) * 16);
      gload_lds16(src + (2048 + t) * 16, d + (2048 + t) * 16);
      gload_lds16(src + (2560 + t) * 16, d + (2560 + t) * 16);
    }
  };

  const int ar = rg * 32 + lr;
  const int aswz = ar * 32 + ((lk ^ ((ar >> 1) & 3)) << 3);
  const int bcol = cg * 32 + lr;
  const int bswz = bcol * 32 + ((lk ^ ((bcol >> 1) & 3)) << 3);

#define LOADB(Btile)                                                               \
    const ushort* Bb = (Btile) + bswz;                                             \
    bf16x8 bh0 = *(const bf16x8*)(Bb);                                             \
    bf16x8 bl0 = *(const bf16x8*)(Bb + 4096);                                      \
    bf16x8 bh1 = *(const bf16x8*)(Bb + 512);                                       \
    bf16x8 bl1 = *(const bf16x8*)(Bb + 4096 + 512);

#define MFMA_S2(pa, pb, pc, pd, Btile)                                             \
  {                                                                                \
    LOADB(Btile)                                                                   \
    pa = __builtin_amdgcn_mfma_f32_16x16x32_bf16(ah0, bh0, pa, 0,0,0);             \
    pa = __builtin_amdgcn_mfma_f32_16x16x32_bf16(ah0, bl0, pa, 0,0,0);             \
    pb = __builtin_amdgcn_mfma_f32_16x16x32_bf16(ah0, bh1, pb, 0,0,0);             \
    pb = __builtin_amdgcn_mfma_f32_16x16x32_bf16(ah0, bl1, pb, 0,0,0);             \
    pc = __builtin_amdgcn_mfma_f32_16x16x32_bf16(ah1, bh0, pc, 0,0,0);             \
    pc = __builtin_amdgcn_mfma_f32_16x16x32_bf16(ah1, bl0, pc, 0,0,0);             \
    pd = __builtin_amdgcn_mfma_f32_16x16x32_bf16(ah1, bh1, pd, 0,0,0);             \
    pd = __builtin_amdgcn_mfma_f32_16x16x32_bf16(ah1, bl1, pd, 0,0,0);             \
  }

#define MFMA_S3(pa, pb, pc, pd, Btile)                                             \
  {                                                                                \
    LOADB(Btile)                                                                   \
    pa = __builtin_amdgcn_mfma_f32_16x16x32_bf16(ah0, bh0, pa, 0,0,0);             \
    pa = __builtin_amdgcn_mfma_f32_16x16x32_bf16(ah0, bl0, pa, 0,0,0);             \
    pa = __builtin_amdgcn_mfma_f32_16x16x32_bf16(al0, bh0, pa, 0,0,0);             \
    pb = __builtin_amdgcn_mfma_f32_16x16x32_bf16(ah0, bh1, pb, 0,0,0);             \
    pb = __builtin_amdgcn_mfma_f32_16x16x32_bf16(ah0, bl1, pb, 0,0,0);             \
    pb = __builtin_amdgcn_mfma_f32_16x16x32_bf16(al0, bh1, pb, 0,0,0);             \
    pc = __builtin_amdgcn_mfma_f32_16x16x32_bf16(ah1, bh0, pc, 0,0,0);             \
    pc = __builtin_amdgcn_mfma_f32_16x16x32_bf16(ah1, bl0, pc, 0,0,0);             \
    pc = __builtin_amdgcn_mfma_f32_16x16x32_bf16(al1, bh0, pc, 0,0,0);             \
    pd = __builtin_amdgcn_mfma_f32_16x16x32_bf16(ah1, bh1, pd, 0,0,0);             \
    pd = __builtin_amdgcn_mfma_f32_16x16x32_bf16(ah1, bl1, pd, 0,0,0);             \
    pd = __builtin_amdgcn_mfma_f32_16x16x32_bf16(al1, bh1, pd, 0,0,0);             \
  }

  loadA(0);
  for (int cp = 0; cp < 20; ++cp) {
    __syncthreads();   // all waves done reading As/Bs of previous chunk
    writeA(cp);
    issueB(cp);
    if (cp < 19) loadA(cp + 1);   // reg prefetch overlaps the drain
    __syncthreads();   // drains vmcnt (Bs ready) + lgkm (As written)
    const ushort* Ab = As + aswz;
    if (cp < 16) {
      bf16x8 ah0 = *(const bf16x8*)(Ab);
      bf16x8 ah1 = *(const bf16x8*)(Ab + 512);
      MFMA_S2(p0_00, p0_01, p0_10, p0_11, Bs);
      MFMA_S2(p1_00, p1_01, p1_10, p1_11, Bs + TILE_US);
      MFMA_S2(p2_00, p2_01, p2_10, p2_11, Bs + 2 * TILE_US);
    } else {
      bf16x8 ah0 = *(const bf16x8*)(Ab);
      bf16x8 al0 = *(const bf16x8*)(Ab + 2048);
      bf16x8 ah1 = *(const bf16x8*)(Ab + 512);
      bf16x8 al1 = *(const bf16x8*)(Ab + 2048 + 512);
      MFMA_S3(p0_00, p0_01, p0_10, p0_11, Bs);
    }
  }
#undef MFMA_S2
#undef MFMA_S3
#undef LOADB

  // ---- epilogue: fold scales + bias, stage out-tile in LDS ----
  __syncthreads();                       // MFMA reads of Bs complete
  float* outT = (float*)Bs;              // [64][132] f32 (34 KB <= 48 KB)
  float bc0 = bias[cg * 32 + lr];
  float bc1 = bias[cg * 32 + 16 + lr];
  f32x4 q0[2][2] = {{p0_00, p0_01}, {p0_10, p0_11}};
  f32x4 q1[2][2] = {{p1_00, p1_01}, {p1_10, p1_11}};
  f32x4 q2[2][2] = {{p2_00, p2_01}, {p2_10, p2_11}};
  #pragma unroll
  for (int fr = 0; fr < 2; ++fr) {
    int lrbase = rg * 32 + fr * 16 + lk * 4;
    #pragma unroll
    for (int q = 0; q < 4; ++q) {
      int lrow = lrbase + q;
      int r = row0 + lrow;
      int rc = (r < NNODES) ? r : (NNODES - 1);
      float s1 = scales[rc * 3 + 1];
      float s2 = scales[rc * 3 + 2];
      outT[lrow * 132 + cg * 32 + lr] =
          q0[fr][0][q] + s1 * q1[fr][0][q] + s2 * q2[fr][0][q] + bc0;
      outT[lrow * 132 + cg * 32 + 16 + lr] =
          q0[fr][1][q] + s1 * q1[fr][1][q] + s2 * q2[fr][1][q] + bc1;
    }
  }
  __syncthreads();

  // ---- LN + relu + residual + bf16-split (wave w handles rows w*8..w*8+7) ----
  int j0 = lane * 2;
  f2 g = *(const f2*)(gam + j0);
  f2 be = *(const f2*)(bet + j0);
  for (int rrow = 0; rrow < 8; ++rrow) {
    int lrow = w * 8 + rrow;
    int r = row0 + lrow;
    f2 v;
    v.x = outT[lrow * 132 + j0];
    v.y = outT[lrow * 132 + j0 + 1];
    float s = v.x + v.y;
    float qq = v.x * v.x + v.y * v.y;
    #pragma unroll
    for (int m = 1; m < 64; m <<= 1) { s += __shfl_xor(s, m, 64); qq += __shfl_xor(qq, m, 64); }
    float mu = s * (1.0f / 128.0f);
    float var = qq * (1.0f / 128.0f) - mu * mu;
    float rstd = rsqrtf(var + 1e-5f);
    f2 o = (v - mu) * rstd * g + be;
    o.x = fmaxf(o.x, 0.f); o.y = fmaxf(o.y, 0.f);
    if (r < NNODES) {
      float* xp = x + (size_t)r * DIM + j0;
      f2 xr = *(const f2*)xp;
      f2 res = o + xr;
      *(f2*)xp = res;
      ushort h0 = bf16_rne(res.x), h1 = bf16_rne(res.y);
      ushort l0 = bf16_rne(res.x - bf16_f(h0)), l1 = bf16_rne(res.y - bf16_f(h1));
      *(uint*)(xho + (size_t)r * DIM + j0) = (uint)h0 | ((uint)h1 << 16);
      *(uint*)(xlo + (size_t)r * DIM + j0) = (uint)l0 | ((uint)l1 << 16);
    }
  }
}

// ---------------- distmult scoring ----------------

__global__ __launch_bounds__(256) void score_k(
    const float* __restrict__ x, const float* __restrict__ qw,
    const int* __restrict__ src, const int* __restrict__ rel,
    const int* __restrict__ dst, float* __restrict__ out)
{
  int wid = blockIdx.x * 4 + (threadIdx.x >> 6);
  if (wid >= NTRIPLES) return;
  int lane = threadIdx.x & 63;
  int j0 = lane * 2;
  int s = src[wid], r = rel[wid], d = dst[wid];
  f2 xs = *(const f2*)(x  + (size_t)s * DIM + j0);
  f2 q  = *(const f2*)(qw + (size_t)r * DIM + j0);
  f2 xd = *(const f2*)(x  + (size_t)d * DIM + j0);
  float p = xs.x*q.x*xd.x + xs.y*q.y*xd.y;
  #pragma unroll
  for (int m = 32; m >= 1; m >>= 1) p += __shfl_xor(p, m, 64);
  if (lane == 0) out[wid] = p;
}

// ---------------- launch ----------------

extern "C" void kernel_launch(void* const* d_in, const int* in_sizes, int n_in,
                              void* d_out, int out_size, void* d_ws, size_t ws_size,
                              hipStream_t stream) {
  const float* x0    = (const float*)d_in[0];
  const int*   ei    = (const int*)d_in[1];
  const int*   etyp  = (const int*)d_in[2];
  const float* ew    = (const float*)d_in[3];
  const float* rel_w = (const float*)d_in[4];
  const float* lin_w = (const float*)d_in[5];
  const float* lin_b = (const float*)d_in[6];
  const float* ln_g  = (const float*)d_in[7];
  const float* lnb   = (const float*)d_in[8];
  const float* qw    = (const float*)d_in[9];
  const int*   srcq  = (const int*)d_in[10];
  const int*   relq  = (const int*)d_in[11];
  const int*   dstq  = (const int*)d_in[12];
  float* out = (float*)d_out;

  char* ws = (char*)d_ws;
  size_t off = 0;
  auto alloc = [&](size_t bytes) -> void* {
    void* p = ws + off; off = (off + bytes + 255) & ~(size_t)255; return p;
  };
  int*    deg       = (int*)alloc((size_t)NNODES * 4);
  int*    row_start = (int*)alloc((size_t)(NNODES + 1) * 4);
  int*    cursor    = (int*)alloc((size_t)NNODES * 4);
  int*    bsum      = (int*)alloc((size_t)(NBLK + 1) * 4);
  int*    bofs      = (int*)alloc((size_t)(NBLK + 1) * 4);
  int*    s_srt     = (int*)alloc((size_t)NEDGES * 4);
  int*    t_srt     = (int*)alloc((size_t)NEDGES * 4);
  float*  w_srt     = (float*)alloc((size_t)NEDGES * 4);
  float*  scales    = (float*)alloc((size_t)NNODES * 3 * 4);
  float*  logsum    = (float*)alloc(256);
  ushort* stats_hi  = (ushort*)alloc((size_t)NNODES * 512 * 2);
  float*  xbuf      = (float*)alloc((size_t)NNODES * DIM * 4);
  ushort* xhi       = (ushort*)alloc((size_t)NNODES * DIM * 2);
  ushort* xlo       = (ushort*)alloc((size_t)NNODES * DIM * 2);
  ushort* wtbuf     = (ushort*)alloc((size_t)NLAYERS * 52 * TILE_US * 2);

  hipMemsetAsync(deg, 0, (size_t)NNODES * 4, stream);
  hipMemsetAsync(logsum, 0, 4, stream);
  deg_hist_k<<<(NEDGES + 255) / 256, 256, 0, stream>>>(ei, deg);
  logsum_k<<<(NNODES + 255) / 256, 256, 0, stream>>>(deg, logsum);
  blocksum_k<<<NBLK, 256, 0, stream>>>(deg, bsum);
  bscan_k<<<1, 256, 0, stream>>>(bsum, bofs);
  csr_offsets_k<<<NBLK, 256, 0, stream>>>(deg, bofs, row_start, cursor);
  scales_k<<<(NNODES + 255) / 256, 256, 0, stream>>>(deg, logsum, scales);
  scatter_k<<<(NEDGES + 255) / 256, 256, 0, stream>>>(ei, etyp, ew, cursor, s_srt, t_srt, w_srt);
  wsplit_k<<<(NLAYERS * KDIM * DIM + 255) / 256, 256, 0, stream>>>(lin_w, wtbuf);
  hipMemcpyAsync(xbuf, x0, (size_t)NNODES * DIM * 4, hipMemcpyDeviceToDevice, stream);
  xsplit_k<<<(NNODES * 64 + 255) / 256, 256, 0, stream>>>(x0, xhi, xlo);

  for (int l = 0; l < NLAYERS; ++l) {
    aggregate_k<<<(NNODES + 3) / 4, 256, 0, stream>>>(
        xhi, x0, rel_w + (size_t)l * NREL * DIM, row_start, s_srt, t_srt, w_srt,
        stats_hi);
    gemm_fused_k<<<(NNODES + 63) / 64, 512, 0, stream>>>(
        stats_hi, xhi, xlo, scales, wtbuf + (size_t)l * 52 * TILE_US,
        lin_b + (size_t)l * DIM, ln_g + (size_t)l * DIM, lnb + (size_t)l * DIM,
        xbuf, xhi, xlo);
  }
  score_k<<<(NTRIPLES + 3) / 4, 256, 0, stream>>>(xbuf, qw, srcq, relq, dstq, out);
}